// Round 14
// baseline (153.910 us; speedup 1.0000x reference)
//
#include <hip/hip_runtime.h>
#include <hip/hip_bf16.h>

#define EPS_F 1e-5f

typedef __attribute__((ext_vector_type(8))) _Float16 f16x8;
typedef __attribute__((ext_vector_type(4))) _Float16 f16x4;
typedef __attribute__((ext_vector_type(4))) float f32x4;

union U16x8 { ushort u[8]; _Float16 h[8]; f16x8 v; };
union U16x4 { ushort u[4]; f16x4 v; };

static __device__ inline ushort f2h(float f) {
  _Float16 h = (_Float16)f;
  return __builtin_bit_cast(ushort, h);
}
static __device__ inline float h2f(ushort u) {
  return (float)__builtin_bit_cast(_Float16, u);
}

// ---------------- prep: weights->f16, sb, rel images, cvtT(x), poolx(x) ----------------
// grid: [0,1608) weights/sb/relimg ; [1608,2120) cvtT ; [2120,2632) poolx
__global__ void __launch_bounds__(256) prep_kernel(
    const float* __restrict__ w_in, const float* __restrict__ a0w,
    const float* __restrict__ a1w, const float* __restrict__ w_out,
    const float* __restrict__ w_res,
    const float* __restrict__ latent, const float* __restrict__ lin_in,
    const float* __restrict__ lin_out,
    const float* __restrict__ a0_rel, const float* __restrict__ a1_rel,
    const float* __restrict__ x,
    ushort* __restrict__ w16, ushort* __restrict__ relimg,
    float* __restrict__ sb_in, float* __restrict__ sb_out,
    ushort* __restrict__ x16, ushort* __restrict__ pool_x) {
  const int gid = blockIdx.x;
  const int tid = threadIdx.x;
  __shared__ __align__(16) char lsm[10240];

  if (gid < 1608) {
    int idx = gid * 256 + tid;
    if (idx < 393216) {
      const float* src; int off;
      if (idx < 32768)       { src = w_in;  off = 0; }
      else if (idx < 163840) { src = a0w;   off = 32768; }
      else if (idx < 294912) { src = a1w;   off = 163840; }
      else if (idx < 360448) { src = w_out; off = 294912; }
      else                   { src = w_res; off = 360448; }
      w16[idx] = f2h(src[idx - off]);
    } else if (idx < 397312) {
      int r = idx - 393216;
      int which = r >> 11;
      int rr = r & 2047;
      int b = rr >> 9, k = rr & 511;
      const float* lin = which ? lin_out : lin_in;
      const float* lv = latent + b * 256;
      const float* lr = lin + k * 256;
      float acc = 0.f;
#pragma unroll 8
      for (int l = 0; l < 256; ++l) acc += lv[l] * lr[l];
      (which ? sb_out : sb_in)[b * 512 + k] = acc;
    } else if (idx < 411648) {
      int e = idx - 397312;
      int which = e >= 7168;
      int s = which ? e - 7168 : e;
      const float* rel = which ? a1_rel : a0_rel;
      ushort val = 0;
      if (s < 2560) {                  // relQ image [128][20], c<8
        int d = s / 20, c = s % 20;
        if (c < 8 && d < 127) val = f2h(rel[c * 127 + d]);
      } else if (s < 5120) {           // relK image, c in 8..15
        int s2 = s - 2560;
        int d = s2 / 20, c = s2 % 20;
        if (c >= 8 && c < 16 && d < 127) val = f2h(rel[c * 127 + d]);
      } else {                         // RV swizzled image
        int pos = (s - 5120) * 2;
        int c = pos >> 8;
        int inner = (pos & 255) ^ ((c & 7) << 4);
        int d = inner >> 1;
        if (d < 127) val = f2h(rel[(16 + c) * 127 + d]);
      }
      relimg[which * 7168 + s] = val;
    }
  } else if (gid < 2120) {
    // cvtT: x f32 (b,128,4096) -> x16 (b,4096,128)
    int e = gid - 1608;
    int pt = e & 31, ct = (e >> 5) & 3, b = e >> 7;
    ushort (*Lt)[40] = (ushort(*)[40])lsm;
#pragma unroll
    for (int r = 0; r < 16; ++r) {
      int e2 = tid + 256 * r;
      int c = e2 >> 7, p = e2 & 127;
      Lt[p][c] = f2h(x[((size_t)(b * 128 + ct * 32 + c)) * 4096 + pt * 128 + p]);
    }
    __syncthreads();
#pragma unroll
    for (int r = 0; r < 2; ++r) {
      int e2 = tid + 256 * r;
      int p = e2 >> 2, q = e2 & 3;
      *(f16x8*)&x16[((size_t)b * 4096 + pt * 128 + p) * 128 + ct * 32 + 8 * q] =
          *(const f16x8*)&Lt[p][8 * q];
    }
  } else {
    // poolx: x f32 -> pool_x (b,1024,128) f16
    int e = gid - 2120;
    int ip = e & 31, ct = (e >> 5) & 3, b = e >> 7;
    float (*Lp)[33] = (float(*)[33])lsm;
    {
      int c = tid >> 3, grp = tid & 7;
      const float* base = x + ((size_t)(b * 128 + ct * 32 + c)) * 4096 + (2 * ip) * 64 + 8 * grp;
      float4 a0 = *(const float4*)&base[0];
      float4 a1 = *(const float4*)&base[4];
      float4 b0 = *(const float4*)&base[64];
      float4 b1 = *(const float4*)&base[68];
      Lp[c][4 * grp + 0] = 0.25f * (a0.x + a0.y + b0.x + b0.y);
      Lp[c][4 * grp + 1] = 0.25f * (a0.z + a0.w + b0.z + b0.w);
      Lp[c][4 * grp + 2] = 0.25f * (a1.x + a1.y + b1.x + b1.y);
      Lp[c][4 * grp + 3] = 0.25f * (a1.z + a1.w + b1.z + b1.w);
    }
    __syncthreads();
    {
      int jp = tid >> 3, q = tid & 7;
      ushort4 o;
      o.x = f2h(Lp[4 * q + 0][jp]);
      o.y = f2h(Lp[4 * q + 1][jp]);
      o.z = f2h(Lp[4 * q + 2][jp]);
      o.w = f2h(Lp[4 * q + 3][jp]);
      *(ushort4*)&pool_x[((size_t)b * 1024 + ip * 32 + jp) * 128 + ct * 32 + 4 * q] = o;
    }
  }
}

// ---------------- MFMA f16 conv1x1, pixel-major (conv_in only) ----------------
// MODE bits: 1 = bn affine, 2 = cbn, 8 = prelu
template <int MODE>
__global__ void __launch_bounds__(256) conv_mfma_kernel(
    const ushort* __restrict__ X, const ushort* __restrict__ W16,
    ushort* __restrict__ Y16, int Cin, int Cout, int P,
    const float* __restrict__ bn, const float* __restrict__ sb,
    const float* __restrict__ alpha) {
  const int tid = threadIdx.x;
  const int p0 = blockIdx.x * 128;
  const int o0 = blockIdx.y * 64;
  const int b  = blockIdx.z;
  const int lane = tid & 63;
  const int wv = tid >> 6;
  const int m = lane & 15, h = lane >> 4;
  const int wr = wv >> 1, wc = wv & 1;

  __shared__ __align__(16) char smem[27648];
  ushort (*Xs)[72] = (ushort(*)[72])smem;
  ushort (*Ws)[72] = (ushort(*)[72])(smem + 18432);
  ushort (*Es)[72] = (ushort(*)[72])smem;

  f32x4 acc[2][4];
#pragma unroll
  for (int i = 0; i < 2; ++i)
#pragma unroll
    for (int j = 0; j < 4; ++j) acc[i][j] = (f32x4){0.f, 0.f, 0.f, 0.f};

  const ushort* Xb = X + (size_t)b * P * Cin;

  for (int k0 = 0; k0 < Cin; k0 += 64) {
    __syncthreads();
#pragma unroll
    for (int r = 0; r < 4; ++r) {
      int e = tid + 256 * r;
      int pp = e >> 3, ch = e & 7;
      *(f16x8*)&Xs[pp][8 * ch] =
          *(const f16x8*)&Xb[(size_t)(p0 + pp) * Cin + k0 + 8 * ch];
    }
#pragma unroll
    for (int r = 0; r < 2; ++r) {
      int e = tid + 256 * r;
      int oc = e >> 3, ch = e & 7;
      *(f16x8*)&Ws[oc][8 * ch] =
          *(const f16x8*)&W16[(size_t)(o0 + oc) * Cin + k0 + 8 * ch];
    }
    __syncthreads();
#pragma unroll
    for (int ks = 0; ks < 2; ++ks) {
      f16x8 af[2], bf[4];
#pragma unroll
      for (int t = 0; t < 2; ++t) af[t] = *(const f16x8*)&Ws[32 * wr + 16 * t + m][32 * ks + 8 * h];
#pragma unroll
      for (int t = 0; t < 4; ++t) bf[t] = *(const f16x8*)&Xs[64 * wc + 16 * t + m][32 * ks + 8 * h];
#pragma unroll
      for (int ta = 0; ta < 2; ++ta)
#pragma unroll
        for (int tb = 0; tb < 4; ++tb)
          acc[ta][tb] = __builtin_amdgcn_mfma_f32_16x16x32_f16(af[ta], bf[tb], acc[ta][tb], 0, 0, 0);
    }
  }

  float scl[2][4], shf[2][4];
#pragma unroll
  for (int ta = 0; ta < 2; ++ta)
#pragma unroll
    for (int r = 0; r < 4; ++r) {
      int oc = o0 + 32 * wr + 16 * ta + 4 * h + r;
      float scale = 1.f, shift = 0.f;
      if (MODE & 1) {
        float sc = bn[oc] * rsqrtf(bn[3 * Cout + oc] + EPS_F);
        scale = sc;
        shift = bn[Cout + oc] - bn[2 * Cout + oc] * sc;
      }
      if (MODE & 2) {
        float ss = sb[b * 2 * Cout + oc];
        float bb = sb[b * 2 * Cout + Cout + oc];
        scale *= ss;
        shift = shift * ss + bb;
      }
      scl[ta][r] = scale; shf[ta][r] = shift;
    }
  float al = (MODE & 8) ? *alpha : 0.f;

  __syncthreads();
#pragma unroll
  for (int ta = 0; ta < 2; ++ta)
#pragma unroll
    for (int tb = 0; tb < 4; ++tb)
#pragma unroll
      for (int r = 0; r < 4; ++r) {
        float v = acc[ta][tb][r] * scl[ta][r] + shf[ta][r];
        if (MODE & 8) v = v > 0.f ? v : al * v;
        Es[64 * wc + 16 * tb + m][32 * wr + 16 * ta + 4 * h + r] = f2h(v);
      }
  __syncthreads();
#pragma unroll
  for (int r = 0; r < 4; ++r) {
    int e = tid + 256 * r;
    int pp = e >> 3, q = e & 7;
    *(f16x8*)&Y16[((size_t)b * P + p0 + pp) * Cout + o0 + 8 * q] =
        *(const f16x8*)&Es[pp][8 * q];
  }
}

// ---------------- fused final: pool(t0)·W_out (cbn) + pool_x·W_res, prelu, f32 out ----------------
__global__ void __launch_bounds__(256) final_fused_kernel(
    const ushort* __restrict__ t0, const ushort* __restrict__ pool_x,
    const ushort* __restrict__ Wo, const ushort* __restrict__ Wr,
    float* __restrict__ Y32,
    const float* __restrict__ bn, const float* __restrict__ sb,
    const float* __restrict__ alpha) {
  const int tid = threadIdx.x;
  const int p0 = blockIdx.x * 128;
  const int o0 = blockIdx.y * 64;
  const int b  = blockIdx.z;
  const int lane = tid & 63;
  const int wv = tid >> 6;
  const int m = lane & 15, h = lane >> 4;
  const int wr = wv >> 1, wc = wv & 1;

  __shared__ __align__(16) char smem[27648];
  ushort (*Xs)[72] = (ushort(*)[72])smem;
  ushort (*Ws)[72] = (ushort(*)[72])(smem + 18432);

  f32x4 acc1[2][4], acc2[2][4];
#pragma unroll
  for (int i = 0; i < 2; ++i)
#pragma unroll
    for (int j = 0; j < 4; ++j) {
      acc1[i][j] = (f32x4){0.f, 0.f, 0.f, 0.f};
      acc2[i][j] = (f32x4){0.f, 0.f, 0.f, 0.f};
    }

  // phase A: pooled t0 (Cin=256) @ W_out -> acc1
  for (int k0 = 0; k0 < 256; k0 += 64) {
    __syncthreads();
#pragma unroll
    for (int r = 0; r < 4; ++r) {
      int e = tid + 256 * r;
      int pp = e >> 3, ch = e & 7;
      int pg = p0 + pp;
      int ip = pg >> 5, jp = pg & 31;
      size_t tb = ((size_t)b * 4096 + ip * 128 + jp * 2) * 256 + k0 + 8 * ch;
      U16x8 a, bb, c, d, o;
      a.v  = *(const f16x8*)&t0[tb];
      bb.v = *(const f16x8*)&t0[tb + 256];
      c.v  = *(const f16x8*)&t0[tb + 64 * 256];
      d.v  = *(const f16x8*)&t0[tb + 65 * 256];
#pragma unroll
      for (int e2 = 0; e2 < 8; ++e2)
        o.h[e2] = ((a.h[e2] + bb.h[e2]) + (c.h[e2] + d.h[e2])) * (_Float16)0.25f;
      *(f16x8*)&Xs[pp][8 * ch] = o.v;
    }
#pragma unroll
    for (int r = 0; r < 2; ++r) {
      int e = tid + 256 * r;
      int oc = e >> 3, ch = e & 7;
      *(f16x8*)&Ws[oc][8 * ch] = *(const f16x8*)&Wo[(size_t)(o0 + oc) * 256 + k0 + 8 * ch];
    }
    __syncthreads();
#pragma unroll
    for (int ks = 0; ks < 2; ++ks) {
      f16x8 af[2], bf[4];
#pragma unroll
      for (int t = 0; t < 2; ++t) af[t] = *(const f16x8*)&Ws[32 * wr + 16 * t + m][32 * ks + 8 * h];
#pragma unroll
      for (int t = 0; t < 4; ++t) bf[t] = *(const f16x8*)&Xs[64 * wc + 16 * t + m][32 * ks + 8 * h];
#pragma unroll
      for (int ta = 0; ta < 2; ++ta)
#pragma unroll
        for (int tb2 = 0; tb2 < 4; ++tb2)
          acc1[ta][tb2] = __builtin_amdgcn_mfma_f32_16x16x32_f16(af[ta], bf[tb2], acc1[ta][tb2], 0, 0, 0);
    }
  }

  // phase B: pool_x (Cin=128) @ W_res -> acc2
  for (int k0 = 0; k0 < 128; k0 += 64) {
    __syncthreads();
#pragma unroll
    for (int r = 0; r < 4; ++r) {
      int e = tid + 256 * r;
      int pp = e >> 3, ch = e & 7;
      *(f16x8*)&Xs[pp][8 * ch] =
          *(const f16x8*)&pool_x[((size_t)b * 1024 + p0 + pp) * 128 + k0 + 8 * ch];
    }
#pragma unroll
    for (int r = 0; r < 2; ++r) {
      int e = tid + 256 * r;
      int oc = e >> 3, ch = e & 7;
      *(f16x8*)&Ws[oc][8 * ch] = *(const f16x8*)&Wr[(size_t)(o0 + oc) * 128 + k0 + 8 * ch];
    }
    __syncthreads();
#pragma unroll
    for (int ks = 0; ks < 2; ++ks) {
      f16x8 af[2], bf[4];
#pragma unroll
      for (int t = 0; t < 2; ++t) af[t] = *(const f16x8*)&Ws[32 * wr + 16 * t + m][32 * ks + 8 * h];
#pragma unroll
      for (int t = 0; t < 4; ++t) bf[t] = *(const f16x8*)&Xs[64 * wc + 16 * t + m][32 * ks + 8 * h];
#pragma unroll
      for (int ta = 0; ta < 2; ++ta)
#pragma unroll
        for (int tb2 = 0; tb2 < 4; ++tb2)
          acc2[ta][tb2] = __builtin_amdgcn_mfma_f32_16x16x32_f16(af[ta], bf[tb2], acc2[ta][tb2], 0, 0, 0);
    }
  }

  const float al = *alpha;
#pragma unroll
  for (int ta = 0; ta < 2; ++ta)
#pragma unroll
    for (int r = 0; r < 4; ++r) {
      int oc = o0 + 32 * wr + 16 * ta + 4 * h + r;
      float sc = bn[oc] * rsqrtf(bn[768 + oc] + EPS_F);
      float shift = bn[256 + oc] - bn[512 + oc] * sc;
      float ss = sb[b * 512 + oc];
      float bb = sb[b * 512 + 256 + oc];
      float scale = sc * ss;
      shift = shift * ss + bb;
#pragma unroll
      for (int tb2 = 0; tb2 < 4; ++tb2) {
        int p = p0 + 64 * wc + 16 * tb2 + m;
        float v = acc1[ta][tb2][r] * scale + shift + acc2[ta][tb2][r];
        v = v > 0.f ? v : al * v;
        Y32[((size_t)b * 256 + oc) * 1024 + p] = v;
      }
    }
}

// ---------------- axial attention + fused qkv conv (direct-global B-frags) ----------------
// Input tin (b, p, 256) with p = i*64 + d1 (i = attended dim).
// Output tout (b, p', 256) with p' = d1*64 + i.  tin != tout (ping-pong).
__global__ void __launch_bounds__(256) axial_attn_kernel(
    const ushort* __restrict__ t0in, const ushort* __restrict__ wqkv,
    const float* __restrict__ bn_qkv,
    const ushort* __restrict__ relimg,
    const float* __restrict__ bn_sim, const float* __restrict__ bn_out,
    ushort* __restrict__ out16) {
  const int tid = threadIdx.x;
  int lin = blockIdx.x;                       // bijective XCD swizzle, bd-major chunks
  int wg = ((lin & 7) << 9) + (lin >> 3);
  const int g  = wg & 15;
  const int bd = wg >> 4;
  const int b  = bd >> 6;
  const int d1 = bd & 63;

  __shared__ __align__(16) char smem[37888];
  // relQ [128][20] @0 | relK @5120 | QK [64][24] @10240
  // QE [64][72] @13312 | KE @22528 | VC swz @31744 | RV swz @33792
  // A2 [64][136] @0 overlay (after barrier C)
#define RQA(d, c)  (smem + (d) * 40 + (c) * 2)
#define RKA(d, c)  (smem + 5120 + (d) * 40 + (c) * 2)
#define QKA(i, c)  (smem + 10240 + (i) * 48 + (c) * 2)
#define QEA(i, k)  (smem + 13312 + (i) * 144 + (k) * 2)
#define KEA(j, k)  (smem + 22528 + (j) * 144 + (k) * 2)
#define VCA(c, j)  (smem + 31744 + ((((c) * 128 + (j) * 2)) ^ (((c) & 7) << 4)))
#define RVA(c, d)  (smem + 33792 + ((((c) * 256 + (d) * 2)) ^ (((c) & 7) << 4)))
#define A2A(i, d)  (smem + (i) * 272 + (d) * 2)

  const int lane = tid & 63;
  const int wv   = tid >> 6;
  const int m    = lane & 15;
  const int h    = lane >> 4;
  const int wr   = wv >> 1, wc = wv & 1;

  // ---- P0: copy rel images ----
  {
    const uint4* img = (const uint4*)relimg;
    for (int u = tid; u < 640; u += 256) ((uint4*)smem)[u] = img[u];   // relQ+relK
    ((uint4*)(smem + 33792))[tid] = img[640 + tid];                    // RV
  }

  // ---- C0: fused qkv conv, B-fragments DIRECT from global (L2-hot), no barriers ----
  f32x4 cacc[2];
  cacc[0] = (f32x4){0.f, 0.f, 0.f, 0.f};
  cacc[1] = (f32x4){0.f, 0.f, 0.f, 0.f};
  {
    const ushort* Xb = t0in + ((size_t)b * 4096 + d1) * 256;
    const ushort* Wg = wqkv + ((size_t)(g * 32 + 16 * wr + m)) * 256;
#pragma unroll
    for (int k0 = 0; k0 < 256; k0 += 64) {
#pragma unroll
      for (int ks = 0; ks < 2; ++ks) {
        f16x8 af = *(const f16x8*)&Wg[k0 + 32 * ks + 8 * h];
#pragma unroll
        for (int tb = 0; tb < 2; ++tb) {
          int i = 32 * wc + 16 * tb + m;
          f16x8 bf = *(const f16x8*)&Xb[(size_t)i * 16384 + k0 + 32 * ks + 8 * h];
          cacc[tb] = __builtin_amdgcn_mfma_f32_16x16x32_f16(af, bf, cacc[tb], 0, 0, 0);
        }
      }
    }
  }
  // C1: epilogue — fold bn_qkv, write QK (wr=0) / VC (wr=1)
  {
    float scl[4], shf[4];
#pragma unroll
    for (int r = 0; r < 4; ++r) {
      int ch = g * 32 + 16 * wr + 4 * h + r;
      float sc = bn_qkv[ch] * rsqrtf(bn_qkv[1536 + ch] + EPS_F);
      scl[r] = sc;
      shf[r] = bn_qkv[512 + ch] - bn_qkv[1024 + ch] * sc;
    }
    if (wr == 0) {
#pragma unroll
      for (int tb = 0; tb < 2; ++tb) {
        int i = 32 * wc + 16 * tb + m;
        U16x4 o;
#pragma unroll
        for (int r = 0; r < 4; ++r) o.u[r] = f2h(cacc[tb][r] * scl[r] + shf[r]);
        *(f16x4*)QKA(i, 4 * h) = o.v;
      }
    } else {
#pragma unroll
      for (int tb = 0; tb < 2; ++tb) {
        int i = 32 * wc + 16 * tb + m;
#pragma unroll
        for (int r = 0; r < 4; ++r)
          *(ushort*)VCA(4 * h + r, i) = f2h(cacc[tb][r] * scl[r] + shf[r]);
      }
    }
  }
  __syncthreads();   // barrier A

  // ---- P1: band-restricted emb GEMM -> dense QE/KE ----
  {
    const int nt = wv;
    const int n = 16 * nt + m;
    f16x4 bqk = *(const f16x4*)QKA(n, 4 * h);
#pragma unroll
    for (int k = 0; k < 5; ++k) {
      int dt = nt + k;
      f16x4 arQ = *(const f16x4*)RQA(16 * dt + m, 4 * h);
      f16x4 arK = *(const f16x4*)RKA(16 * dt + m, 4 * h);
      f32x4 dq = __builtin_amdgcn_mfma_f32_16x16x16f16(arQ, bqk, (f32x4){0.f,0.f,0.f,0.f}, 0, 0, 0);
      f32x4 dk = __builtin_amdgcn_mfma_f32_16x16x16f16(arK, bqk, (f32x4){0.f,0.f,0.f,0.f}, 0, 0, 0);
#pragma unroll
      for (int r = 0; r < 4; ++r) {
        int d = 16 * dt + 4 * h + r;
        int i = n - d + 63;
        if (k == 0 || k == 4) {
          if ((unsigned)i < 64u) {
            *(ushort*)QEA(i, n) = f2h(dq[r]);
            *(ushort*)KEA(i, n) = f2h(dk[r]);
          }
        } else {
          *(ushort*)QEA(i, n) = f2h(dq[r]);
          *(ushort*)KEA(i, n) = f2h(dk[r]);
        }
      }
    }
  }
  __syncthreads();   // barrier B

  // ---- P2: sim ----
  f32x4 acc[4];
#pragma unroll
  for (int tj = 0; tj < 4; ++tj) acc[tj] = (f32x4){0.f, 0.f, 0.f, 0.f};
  {
    const int ia = 16 * wv + m;
    f16x8 af0 = *(const f16x8*)QEA(ia, 8 * h);
    f16x8 af1 = *(const f16x8*)QEA(ia, 32 + 8 * h);
#pragma unroll
    for (int tj = 0; tj < 4; ++tj) {
      int j = 16 * tj + m;
      f16x8 bf0 = *(const f16x8*)KEA(j, 8 * h);
      f16x8 bf1 = *(const f16x8*)KEA(j, 32 + 8 * h);
      acc[tj] = __builtin_amdgcn_mfma_f32_16x16x32_f16(af0, bf0, acc[tj], 0, 0, 0);
      acc[tj] = __builtin_amdgcn_mfma_f32_16x16x32_f16(af1, bf1, acc[tj], 0, 0, 0);
    }
  }

  float s_qk = bn_sim[g]      * rsqrtf(bn_sim[144 + g] + EPS_F);
  float s_qe = bn_sim[16 + g] * rsqrtf(bn_sim[160 + g] + EPS_F);
  float s_ke = bn_sim[32 + g] * rsqrtf(bn_sim[176 + g] + EPS_F);
  float sh   = (bn_sim[48 + g] - bn_sim[96 + g]  * s_qk)
             + (bn_sim[64 + g] - bn_sim[112 + g] * s_qe)
             + (bn_sim[80 + g] - bn_sim[128 + g] * s_ke);

  const int ib = 16 * wv + 4 * h;
  float sv[4][4];
#pragma unroll
  for (int tj = 0; tj < 4; ++tj) {
    int j = 16 * tj + m;
    f16x4 qe4 = *(const f16x4*)QEA(j, ib);
    f16x4 ke4 = *(const f16x4*)KEA(j, ib);
#pragma unroll
    for (int r = 0; r < 4; ++r)
      sv[tj][r] = acc[tj][r] * s_qk + (float)qe4[r] * s_qe + (float)ke4[r] * s_ke + sh;
  }

  // ---- P3: softmax over j ----
  float p[4][4];
  {
    float mx[4];
#pragma unroll
    for (int r = 0; r < 4; ++r) {
      float v = fmaxf(fmaxf(sv[0][r], sv[1][r]), fmaxf(sv[2][r], sv[3][r]));
      v = fmaxf(v, __shfl_xor(v, 1));
      v = fmaxf(v, __shfl_xor(v, 2));
      v = fmaxf(v, __shfl_xor(v, 4));
      v = fmaxf(v, __shfl_xor(v, 8));
      mx[r] = v;
    }
#pragma unroll
    for (int r = 0; r < 4; ++r) {
      float ssum = 0.f;
#pragma unroll
      for (int tj = 0; tj < 4; ++tj) {
        p[tj][r] = __expf(sv[tj][r] - mx[r]);
        ssum += p[tj][r];
      }
      ssum += __shfl_xor(ssum, 1);
      ssum += __shfl_xor(ssum, 2);
      ssum += __shfl_xor(ssum, 4);
      ssum += __shfl_xor(ssum, 8);
      float inv = 1.f / ssum;
#pragma unroll
      for (int tj = 0; tj < 4; ++tj) p[tj][r] *= inv;
    }
  }

  __syncthreads();   // barrier C

  // ---- P4: wave-private zero of A2 rows [16wv,16wv+16), then scatter ----
  {
    uint4 z = make_uint4(0u, 0u, 0u, 0u);
    uint4* base = (uint4*)(smem + wv * 4352);
#pragma unroll
    for (int u = 0; u < 4; ++u) base[lane + 64 * u] = z;
    if (lane < 16) base[lane + 256] = z;
  }
#pragma unroll
  for (int tj = 0; tj < 4; ++tj) {
    int j = 16 * tj + m;
#pragma unroll
    for (int r = 0; r < 4; ++r) {
      int i = ib + r;
      *(ushort*)A2A(i, i - j + 63) = f2h(p[tj][r]);
    }
  }

  // ---- P5: att / att_e ----
  f32x4 accA = (f32x4){0.f, 0.f, 0.f, 0.f};
  f32x4 accE = (f32x4){0.f, 0.f, 0.f, 0.f};
  {
    const int ia = 16 * wv + m;
#pragma unroll
    for (int ks = 0; ks < 2; ++ks) {
      U16x8 pa;
#pragma unroll
      for (int e = 0; e < 8; ++e) {
        int j = 32 * ks + 8 * h + e;
        pa.u[e] = *(ushort*)A2A(ia, ia - j + 63);
      }
      f16x8 vb = *(const f16x8*)VCA(m, 32 * ks + 8 * h);
      accA = __builtin_amdgcn_mfma_f32_16x16x32_f16(pa.v, vb, accA, 0, 0, 0);
    }
#pragma unroll
    for (int ks = 0; ks < 4; ++ks) {
      f16x8 pe = *(const f16x8*)A2A(ia, 32 * ks + 8 * h);
      f16x8 rv = *(const f16x8*)RVA(m, 32 * ks + 8 * h);
      accE = __builtin_amdgcn_mfma_f32_16x16x32_f16(pe, rv, accE, 0, 0, 0);
    }
  }

  // ---- P6: fold bn_out, pixel-major write ----
  {
    int oc = g * 16 + m;
    int c0 = 2 * oc, c1 = c0 + 1;
    float sc0 = bn_out[c0] * rsqrtf(bn_out[1536 + c0] + EPS_F);
    float sh0 = bn_out[512 + c0] - bn_out[1024 + c0] * sc0;
    float sc1 = bn_out[c1] * rsqrtf(bn_out[1536 + c1] + EPS_F);
    float sh1 = bn_out[512 + c1] - bn_out[1024 + c1] * sc1;
    float vv[4];
    vv[0] = accA[0] * sc0 + accE[0] * sc1 + sh0 + sh1;
    vv[1] = accA[1] * sc0 + accE[1] * sc1 + sh0 + sh1;
    vv[2] = accA[2] * sc0 + accE[2] * sc1 + sh0 + sh1;
    vv[3] = accA[3] * sc0 + accE[3] * sc1 + sh0 + sh1;
    size_t base = ((size_t)b * 4096 + (size_t)d1 * 64 + ib) * 256 + oc;
#pragma unroll
    for (int r = 0; r < 4; ++r)
      out16[base + (size_t)r * 256] = f2h(vv[r]);
  }
#undef RQA
#undef RKA
#undef QKA
#undef QEA
#undef KEA
#undef VCA
#undef RVA
#undef A2A
}

extern "C" void kernel_launch(void* const* d_in, const int* in_sizes, int n_in,
                              void* d_out, int out_size, void* d_ws, size_t ws_size,
                              hipStream_t stream) {
  const float* x         = (const float*)d_in[0];
  const float* latent    = (const float*)d_in[1];
  const float* w_in      = (const float*)d_in[2];
  const float* bn_in     = (const float*)d_in[3];
  const float* lin_in    = (const float*)d_in[4];
  const float* alpha_in  = (const float*)d_in[5];
  const float* a0_wqkv   = (const float*)d_in[6];
  const float* a0_bn_qkv = (const float*)d_in[7];
  const float* a0_bn_sim = (const float*)d_in[8];
  const float* a0_bn_out = (const float*)d_in[9];
  const float* a0_rel    = (const float*)d_in[10];
  const float* a1_wqkv   = (const float*)d_in[11];
  const float* a1_bn_qkv = (const float*)d_in[12];
  const float* a1_bn_sim = (const float*)d_in[13];
  const float* a1_bn_out = (const float*)d_in[14];
  const float* a1_rel    = (const float*)d_in[15];
  const float* w_out     = (const float*)d_in[16];
  const float* bn_outp   = (const float*)d_in[17];
  const float* lin_out   = (const float*)d_in[18];
  const float* w_res     = (const float*)d_in[19];
  const float* alpha_fin = (const float*)d_in[20];

  float* ws = (float*)d_ws;
  float* sb_in  = ws;                          // 2048 f
  float* sb_out = ws + 2048;                   // 2048 f
  ushort* w16   = (ushort*)(ws + 4096);        // 393216 u16
  ushort* relimg = w16 + 393216;               // 14336 u16
  ushort* x16   = relimg + 14336;              // 2097152 u16 (b,4096,128)
  ushort* t0    = x16 + 2097152;               // 4194304 u16 (b,4096,256)
  ushort* t1    = t0 + 4194304;                // 4194304 u16 (b,4096,256) ping-pong
  ushort* pool_x = t1 + 4194304;               // 524288 u16  (b,1024,128)

  ushort* w_in16  = w16;
  ushort* a0w16   = w16 + 32768;
  ushort* a1w16   = w16 + 163840;
  ushort* w_out16 = w16 + 294912;
  ushort* w_res16 = w16 + 360448;
  ushort* rimg_a  = relimg;
  ushort* rimg_b  = relimg + 7168;

  // prep: weights/sb/relimg + cvtT(x) + poolx(x)
  prep_kernel<<<2632, 256, 0, stream>>>(w_in, a0_wqkv, a1_wqkv, w_out, w_res,
                                        latent, lin_in, lin_out, a0_rel, a1_rel,
                                        x, w16, relimg, sb_in, sb_out, x16, pool_x);

  // conv_in + cbn + prelu -> t0 (pixel-major, p = h*64+w)
  conv_mfma_kernel<11><<<dim3(32, 4, 4), 256, 0, stream>>>(
      x16, w_in16, t0, 128, 256, 4096, bn_in, sb_in, alpha_in);

  // axial 0 over H (i=h, d1=w), fused qkv conv: t0 -> t1 (out p = w*64+h)
  axial_attn_kernel<<<4096, 256, 0, stream>>>(
      t0, a0w16, a0_bn_qkv, rimg_a, a0_bn_sim, a0_bn_out, t1);

  // axial 1 over W (i=w, d1=h), fused qkv conv: t1 -> t0 (out p = h*64+w, std)
  axial_attn_kernel<<<4096, 256, 0, stream>>>(
      t1, a1w16, a1_bn_qkv, rimg_b, a1_bn_sim, a1_bn_out, t0);

  // fused: pool(t0)@W_out (cbn) + pool_x@W_res, prelu -> d_out (f32 chan-major)
  final_fused_kernel<<<dim3(8, 4, 4), 256, 0, stream>>>(
      t0, pool_x, w_out16, w_res16, (float*)d_out, bn_outp, sb_out, alpha_fin);
}

// Round 15
// 131.802 us; speedup vs baseline: 1.1677x; 1.1677x over previous
//
#include <hip/hip_runtime.h>
#include <hip/hip_bf16.h>

#define EPS_F 1e-5f

typedef __attribute__((ext_vector_type(8))) _Float16 f16x8;
typedef __attribute__((ext_vector_type(4))) _Float16 f16x4;
typedef __attribute__((ext_vector_type(4))) float f32x4;

union U16x8 { ushort u[8]; _Float16 h[8]; f16x8 v; };
union U16x4 { ushort u[4]; f16x4 v; };

static __device__ inline ushort f2h(float f) {
  _Float16 h = (_Float16)f;
  return __builtin_bit_cast(ushort, h);
}
static __device__ inline float h2f(ushort u) {
  return (float)__builtin_bit_cast(_Float16, u);
}

// ---------------- prep: weights->f16, sb, rel images, cvtT(x), poolx(x) ----------------
// grid: [0,1608) weights/sb/relimg ; [1608,2120) cvtT ; [2120,2632) poolx
__global__ void __launch_bounds__(256) prep_kernel(
    const float* __restrict__ w_in, const float* __restrict__ a0w,
    const float* __restrict__ a1w, const float* __restrict__ w_out,
    const float* __restrict__ w_res,
    const float* __restrict__ latent, const float* __restrict__ lin_in,
    const float* __restrict__ lin_out,
    const float* __restrict__ a0_rel, const float* __restrict__ a1_rel,
    const float* __restrict__ x,
    ushort* __restrict__ w16, ushort* __restrict__ relimg,
    float* __restrict__ sb_in, float* __restrict__ sb_out,
    ushort* __restrict__ x16, ushort* __restrict__ pool_x) {
  const int gid = blockIdx.x;
  const int tid = threadIdx.x;
  __shared__ __align__(16) char lsm[10240];

  if (gid < 1608) {
    int idx = gid * 256 + tid;
    if (idx < 393216) {
      const float* src; int off;
      if (idx < 32768)       { src = w_in;  off = 0; }
      else if (idx < 163840) { src = a0w;   off = 32768; }
      else if (idx < 294912) { src = a1w;   off = 163840; }
      else if (idx < 360448) { src = w_out; off = 294912; }
      else                   { src = w_res; off = 360448; }
      w16[idx] = f2h(src[idx - off]);
    } else if (idx < 397312) {
      int r = idx - 393216;
      int which = r >> 11;
      int rr = r & 2047;
      int b = rr >> 9, k = rr & 511;
      const float* lin = which ? lin_out : lin_in;
      const float* lv = latent + b * 256;
      const float* lr = lin + k * 256;
      float acc = 0.f;
#pragma unroll 8
      for (int l = 0; l < 256; ++l) acc += lv[l] * lr[l];
      (which ? sb_out : sb_in)[b * 512 + k] = acc;
    } else if (idx < 411648) {
      int e = idx - 397312;
      int which = e >= 7168;
      int s = which ? e - 7168 : e;
      const float* rel = which ? a1_rel : a0_rel;
      ushort val = 0;
      if (s < 2560) {                  // relQ image [128][20], c<8
        int d = s / 20, c = s % 20;
        if (c < 8 && d < 127) val = f2h(rel[c * 127 + d]);
      } else if (s < 5120) {           // relK image, c in 8..15
        int s2 = s - 2560;
        int d = s2 / 20, c = s2 % 20;
        if (c >= 8 && c < 16 && d < 127) val = f2h(rel[c * 127 + d]);
      } else {                         // RV swizzled image
        int pos = (s - 5120) * 2;
        int c = pos >> 8;
        int inner = (pos & 255) ^ ((c & 7) << 4);
        int d = inner >> 1;
        if (d < 127) val = f2h(rel[(16 + c) * 127 + d]);
      }
      relimg[which * 7168 + s] = val;
    }
  } else if (gid < 2120) {
    // cvtT: x f32 (b,128,4096) -> x16 (b,4096,128)
    int e = gid - 1608;
    int pt = e & 31, ct = (e >> 5) & 3, b = e >> 7;
    ushort (*Lt)[40] = (ushort(*)[40])lsm;
#pragma unroll
    for (int r = 0; r < 16; ++r) {
      int e2 = tid + 256 * r;
      int c = e2 >> 7, p = e2 & 127;
      Lt[p][c] = f2h(x[((size_t)(b * 128 + ct * 32 + c)) * 4096 + pt * 128 + p]);
    }
    __syncthreads();
#pragma unroll
    for (int r = 0; r < 2; ++r) {
      int e2 = tid + 256 * r;
      int p = e2 >> 2, q = e2 & 3;
      *(f16x8*)&x16[((size_t)b * 4096 + pt * 128 + p) * 128 + ct * 32 + 8 * q] =
          *(const f16x8*)&Lt[p][8 * q];
    }
  } else {
    // poolx: x f32 -> pool_x (b,1024,128) f16
    int e = gid - 2120;
    int ip = e & 31, ct = (e >> 5) & 3, b = e >> 7;
    float (*Lp)[33] = (float(*)[33])lsm;
    {
      int c = tid >> 3, grp = tid & 7;
      const float* base = x + ((size_t)(b * 128 + ct * 32 + c)) * 4096 + (2 * ip) * 64 + 8 * grp;
      float4 a0 = *(const float4*)&base[0];
      float4 a1 = *(const float4*)&base[4];
      float4 b0 = *(const float4*)&base[64];
      float4 b1 = *(const float4*)&base[68];
      Lp[c][4 * grp + 0] = 0.25f * (a0.x + a0.y + b0.x + b0.y);
      Lp[c][4 * grp + 1] = 0.25f * (a0.z + a0.w + b0.z + b0.w);
      Lp[c][4 * grp + 2] = 0.25f * (a1.x + a1.y + b1.x + b1.y);
      Lp[c][4 * grp + 3] = 0.25f * (a1.z + a1.w + b1.z + b1.w);
    }
    __syncthreads();
    {
      int jp = tid >> 3, q = tid & 7;
      ushort4 o;
      o.x = f2h(Lp[4 * q + 0][jp]);
      o.y = f2h(Lp[4 * q + 1][jp]);
      o.z = f2h(Lp[4 * q + 2][jp]);
      o.w = f2h(Lp[4 * q + 3][jp]);
      *(ushort4*)&pool_x[((size_t)b * 1024 + ip * 32 + jp) * 128 + ct * 32 + 4 * q] = o;
    }
  }
}

// ---------------- MFMA f16 conv1x1, pixel-major (conv_in only) ----------------
// MODE bits: 1 = bn affine, 2 = cbn, 8 = prelu
template <int MODE>
__global__ void __launch_bounds__(256) conv_mfma_kernel(
    const ushort* __restrict__ X, const ushort* __restrict__ W16,
    ushort* __restrict__ Y16, int Cin, int Cout, int P,
    const float* __restrict__ bn, const float* __restrict__ sb,
    const float* __restrict__ alpha) {
  const int tid = threadIdx.x;
  const int p0 = blockIdx.x * 128;
  const int o0 = blockIdx.y * 64;
  const int b  = blockIdx.z;
  const int lane = tid & 63;
  const int wv = tid >> 6;
  const int m = lane & 15, h = lane >> 4;
  const int wr = wv >> 1, wc = wv & 1;

  __shared__ __align__(16) char smem[27648];
  ushort (*Xs)[72] = (ushort(*)[72])smem;
  ushort (*Ws)[72] = (ushort(*)[72])(smem + 18432);
  ushort (*Es)[72] = (ushort(*)[72])smem;

  f32x4 acc[2][4];
#pragma unroll
  for (int i = 0; i < 2; ++i)
#pragma unroll
    for (int j = 0; j < 4; ++j) acc[i][j] = (f32x4){0.f, 0.f, 0.f, 0.f};

  const ushort* Xb = X + (size_t)b * P * Cin;

  for (int k0 = 0; k0 < Cin; k0 += 64) {
    __syncthreads();
#pragma unroll
    for (int r = 0; r < 4; ++r) {
      int e = tid + 256 * r;
      int pp = e >> 3, ch = e & 7;
      *(f16x8*)&Xs[pp][8 * ch] =
          *(const f16x8*)&Xb[(size_t)(p0 + pp) * Cin + k0 + 8 * ch];
    }
#pragma unroll
    for (int r = 0; r < 2; ++r) {
      int e = tid + 256 * r;
      int oc = e >> 3, ch = e & 7;
      *(f16x8*)&Ws[oc][8 * ch] =
          *(const f16x8*)&W16[(size_t)(o0 + oc) * Cin + k0 + 8 * ch];
    }
    __syncthreads();
#pragma unroll
    for (int ks = 0; ks < 2; ++ks) {
      f16x8 af[2], bf[4];
#pragma unroll
      for (int t = 0; t < 2; ++t) af[t] = *(const f16x8*)&Ws[32 * wr + 16 * t + m][32 * ks + 8 * h];
#pragma unroll
      for (int t = 0; t < 4; ++t) bf[t] = *(const f16x8*)&Xs[64 * wc + 16 * t + m][32 * ks + 8 * h];
#pragma unroll
      for (int ta = 0; ta < 2; ++ta)
#pragma unroll
        for (int tb = 0; tb < 4; ++tb)
          acc[ta][tb] = __builtin_amdgcn_mfma_f32_16x16x32_f16(af[ta], bf[tb], acc[ta][tb], 0, 0, 0);
    }
  }

  float scl[2][4], shf[2][4];
#pragma unroll
  for (int ta = 0; ta < 2; ++ta)
#pragma unroll
    for (int r = 0; r < 4; ++r) {
      int oc = o0 + 32 * wr + 16 * ta + 4 * h + r;
      float scale = 1.f, shift = 0.f;
      if (MODE & 1) {
        float sc = bn[oc] * rsqrtf(bn[3 * Cout + oc] + EPS_F);
        scale = sc;
        shift = bn[Cout + oc] - bn[2 * Cout + oc] * sc;
      }
      if (MODE & 2) {
        float ss = sb[b * 2 * Cout + oc];
        float bb = sb[b * 2 * Cout + Cout + oc];
        scale *= ss;
        shift = shift * ss + bb;
      }
      scl[ta][r] = scale; shf[ta][r] = shift;
    }
  float al = (MODE & 8) ? *alpha : 0.f;

  __syncthreads();
#pragma unroll
  for (int ta = 0; ta < 2; ++ta)
#pragma unroll
    for (int tb = 0; tb < 4; ++tb)
#pragma unroll
      for (int r = 0; r < 4; ++r) {
        float v = acc[ta][tb][r] * scl[ta][r] + shf[ta][r];
        if (MODE & 8) v = v > 0.f ? v : al * v;
        Es[64 * wc + 16 * tb + m][32 * wr + 16 * ta + 4 * h + r] = f2h(v);
      }
  __syncthreads();
#pragma unroll
  for (int r = 0; r < 4; ++r) {
    int e = tid + 256 * r;
    int pp = e >> 3, q = e & 7;
    *(f16x8*)&Y16[((size_t)b * P + p0 + pp) * Cout + o0 + 8 * q] =
        *(const f16x8*)&Es[pp][8 * q];
  }
}

// ---------------- fused final: pool(t0)·W_out (cbn) + pool_x·W_res, prelu, f32 out ----------------
__global__ void __launch_bounds__(256) final_fused_kernel(
    const ushort* __restrict__ t0, const ushort* __restrict__ pool_x,
    const ushort* __restrict__ Wo, const ushort* __restrict__ Wr,
    float* __restrict__ Y32,
    const float* __restrict__ bn, const float* __restrict__ sb,
    const float* __restrict__ alpha) {
  const int tid = threadIdx.x;
  const int p0 = blockIdx.x * 128;
  const int o0 = blockIdx.y * 64;
  const int b  = blockIdx.z;
  const int lane = tid & 63;
  const int wv = tid >> 6;
  const int m = lane & 15, h = lane >> 4;
  const int wr = wv >> 1, wc = wv & 1;

  __shared__ __align__(16) char smem[27648];
  ushort (*Xs)[72] = (ushort(*)[72])smem;
  ushort (*Ws)[72] = (ushort(*)[72])(smem + 18432);

  f32x4 acc1[2][4], acc2[2][4];
#pragma unroll
  for (int i = 0; i < 2; ++i)
#pragma unroll
    for (int j = 0; j < 4; ++j) {
      acc1[i][j] = (f32x4){0.f, 0.f, 0.f, 0.f};
      acc2[i][j] = (f32x4){0.f, 0.f, 0.f, 0.f};
    }

  // phase A: pooled t0 (Cin=256) @ W_out -> acc1
  for (int k0 = 0; k0 < 256; k0 += 64) {
    __syncthreads();
#pragma unroll
    for (int r = 0; r < 4; ++r) {
      int e = tid + 256 * r;
      int pp = e >> 3, ch = e & 7;
      int pg = p0 + pp;
      int ip = pg >> 5, jp = pg & 31;
      size_t tb = ((size_t)b * 4096 + ip * 128 + jp * 2) * 256 + k0 + 8 * ch;
      U16x8 a, bb, c, d, o;
      a.v  = *(const f16x8*)&t0[tb];
      bb.v = *(const f16x8*)&t0[tb + 256];
      c.v  = *(const f16x8*)&t0[tb + 64 * 256];
      d.v  = *(const f16x8*)&t0[tb + 65 * 256];
#pragma unroll
      for (int e2 = 0; e2 < 8; ++e2)
        o.h[e2] = ((a.h[e2] + bb.h[e2]) + (c.h[e2] + d.h[e2])) * (_Float16)0.25f;
      *(f16x8*)&Xs[pp][8 * ch] = o.v;
    }
#pragma unroll
    for (int r = 0; r < 2; ++r) {
      int e = tid + 256 * r;
      int oc = e >> 3, ch = e & 7;
      *(f16x8*)&Ws[oc][8 * ch] = *(const f16x8*)&Wo[(size_t)(o0 + oc) * 256 + k0 + 8 * ch];
    }
    __syncthreads();
#pragma unroll
    for (int ks = 0; ks < 2; ++ks) {
      f16x8 af[2], bf[4];
#pragma unroll
      for (int t = 0; t < 2; ++t) af[t] = *(const f16x8*)&Ws[32 * wr + 16 * t + m][32 * ks + 8 * h];
#pragma unroll
      for (int t = 0; t < 4; ++t) bf[t] = *(const f16x8*)&Xs[64 * wc + 16 * t + m][32 * ks + 8 * h];
#pragma unroll
      for (int ta = 0; ta < 2; ++ta)
#pragma unroll
        for (int tb2 = 0; tb2 < 4; ++tb2)
          acc1[ta][tb2] = __builtin_amdgcn_mfma_f32_16x16x32_f16(af[ta], bf[tb2], acc1[ta][tb2], 0, 0, 0);
    }
  }

  // phase B: pool_x (Cin=128) @ W_res -> acc2
  for (int k0 = 0; k0 < 128; k0 += 64) {
    __syncthreads();
#pragma unroll
    for (int r = 0; r < 4; ++r) {
      int e = tid + 256 * r;
      int pp = e >> 3, ch = e & 7;
      *(f16x8*)&Xs[pp][8 * ch] =
          *(const f16x8*)&pool_x[((size_t)b * 1024 + p0 + pp) * 128 + k0 + 8 * ch];
    }
#pragma unroll
    for (int r = 0; r < 2; ++r) {
      int e = tid + 256 * r;
      int oc = e >> 3, ch = e & 7;
      *(f16x8*)&Ws[oc][8 * ch] = *(const f16x8*)&Wr[(size_t)(o0 + oc) * 128 + k0 + 8 * ch];
    }
    __syncthreads();
#pragma unroll
    for (int ks = 0; ks < 2; ++ks) {
      f16x8 af[2], bf[4];
#pragma unroll
      for (int t = 0; t < 2; ++t) af[t] = *(const f16x8*)&Ws[32 * wr + 16 * t + m][32 * ks + 8 * h];
#pragma unroll
      for (int t = 0; t < 4; ++t) bf[t] = *(const f16x8*)&Xs[64 * wc + 16 * t + m][32 * ks + 8 * h];
#pragma unroll
      for (int ta = 0; ta < 2; ++ta)
#pragma unroll
        for (int tb2 = 0; tb2 < 4; ++tb2)
          acc2[ta][tb2] = __builtin_amdgcn_mfma_f32_16x16x32_f16(af[ta], bf[tb2], acc2[ta][tb2], 0, 0, 0);
    }
  }

  const float al = *alpha;
#pragma unroll
  for (int ta = 0; ta < 2; ++ta)
#pragma unroll
    for (int r = 0; r < 4; ++r) {
      int oc = o0 + 32 * wr + 16 * ta + 4 * h + r;
      float sc = bn[oc] * rsqrtf(bn[768 + oc] + EPS_F);
      float shift = bn[256 + oc] - bn[512 + oc] * sc;
      float ss = sb[b * 512 + oc];
      float bb = sb[b * 512 + 256 + oc];
      float scale = sc * ss;
      shift = shift * ss + bb;
#pragma unroll
      for (int tb2 = 0; tb2 < 4; ++tb2) {
        int p = p0 + 64 * wc + 16 * tb2 + m;
        float v = acc1[ta][tb2][r] * scale + shift + acc2[ta][tb2][r];
        v = v > 0.f ? v : al * v;
        Y32[((size_t)b * 256 + oc) * 1024 + p] = v;
      }
    }
}

// ---------------- axial attention + fused qkv conv (double-buffered LDS staging) ----------------
// Input tin (b, p, 256) with p = i*64 + d1 (i = attended dim).
// Output tout (b, p', 256) with p' = d1*64 + i.  tin != tout (ping-pong).
__global__ void __launch_bounds__(256) axial_attn_kernel(
    const ushort* __restrict__ t0in, const ushort* __restrict__ wqkv,
    const float* __restrict__ bn_qkv,
    const ushort* __restrict__ relimg,
    const float* __restrict__ bn_sim, const float* __restrict__ bn_out,
    ushort* __restrict__ out16) {
  const int tid = threadIdx.x;
  int lin = blockIdx.x;                       // bijective XCD swizzle, bd-major chunks
  int wg = ((lin & 7) << 9) + (lin >> 3);
  const int g  = wg & 15;
  const int bd = wg >> 4;
  const int b  = bd >> 6;
  const int d1 = bd & 63;

  __shared__ __align__(16) char smem[37888];
  // relQ [128][20] @0 | relK @5120 | QK [64][24] @10240
  // QE [64][72] @13312 (= C0 staging buf0) | KE @22528 (= buf1) | VC swz @31744
  // RV swz @33792 | A2 [64][136] @0 overlay
#define RQA(d, c)  (smem + (d) * 40 + (c) * 2)
#define RKA(d, c)  (smem + 5120 + (d) * 40 + (c) * 2)
#define QKA(i, c)  (smem + 10240 + (i) * 48 + (c) * 2)
#define QEA(i, k)  (smem + 13312 + (i) * 144 + (k) * 2)
#define KEA(j, k)  (smem + 22528 + (j) * 144 + (k) * 2)
#define VCA(c, j)  (smem + 31744 + ((((c) * 128 + (j) * 2)) ^ (((c) & 7) << 4)))
#define RVA(c, d)  (smem + 33792 + ((((c) * 256 + (d) * 2)) ^ (((c) & 7) << 4)))
#define A2A(i, d)  (smem + (i) * 272 + (d) * 2)

  const int lane = tid & 63;
  const int wv   = tid >> 6;
  const int m    = lane & 15;
  const int h    = lane >> 4;
  const int wr   = wv >> 1, wc = wv & 1;

  // ---- P0: copy rel images ----
  {
    const uint4* img = (const uint4*)relimg;
    for (int u = tid; u < 640; u += 256) ((uint4*)smem)[u] = img[u];   // relQ+relK
    ((uint4*)(smem + 33792))[tid] = img[640 + tid];                    // RV
  }

  // ---- C0: fused qkv conv, double-buffered LDS staging (buf0=QE region, buf1=KE) ----
  f32x4 cacc[2];
  cacc[0] = (f32x4){0.f, 0.f, 0.f, 0.f};
  cacc[1] = (f32x4){0.f, 0.f, 0.f, 0.f};
  {
    const ushort* Xb = t0in + ((size_t)b * 4096 + d1) * 256;
    const ushort* Wg = wqkv + ((size_t)(g * 32 + 16 * wr + m)) * 256;
    char* const XS0 = smem + 13312;
    char* const XS1 = smem + 22528;
    const int si = tid >> 3, ssub = tid & 7;   // stage: pixel si (+32), chan-octet ssub
    // stage chunk 0 -> XS0
#pragma unroll
    for (int r = 0; r < 2; ++r) {
      int i = si + 32 * r;
      *(f16x8*)(XS0 + i * 144 + ssub * 16) =
          *(const f16x8*)&Xb[(size_t)i * 16384 + 8 * ssub];
    }
    __syncthreads();
#pragma unroll
    for (int c = 0; c < 4; ++c) {
      char* cur = (c & 1) ? XS1 : XS0;
      if (c < 3) {
        char* nxt = (c & 1) ? XS0 : XS1;
#pragma unroll
        for (int r = 0; r < 2; ++r) {
          int i = si + 32 * r;
          *(f16x8*)(nxt + i * 144 + ssub * 16) =
              *(const f16x8*)&Xb[(size_t)i * 16384 + (c + 1) * 64 + 8 * ssub];
        }
      }
#pragma unroll
      for (int ks = 0; ks < 2; ++ks) {
        f16x8 af = *(const f16x8*)&Wg[c * 64 + 32 * ks + 8 * h];
#pragma unroll
        for (int tb = 0; tb < 2; ++tb) {
          int i = 32 * wc + 16 * tb + m;
          f16x8 bf = *(const f16x8*)(cur + i * 144 + (32 * ks + 8 * h) * 2);
          cacc[tb] = __builtin_amdgcn_mfma_f32_16x16x32_f16(af, bf, cacc[tb], 0, 0, 0);
        }
      }
      __syncthreads();
    }
  }
  // C1: epilogue — fold bn_qkv, write QK (wr=0) / VC (wr=1)
  {
    float scl[4], shf[4];
#pragma unroll
    for (int r = 0; r < 4; ++r) {
      int ch = g * 32 + 16 * wr + 4 * h + r;
      float sc = bn_qkv[ch] * rsqrtf(bn_qkv[1536 + ch] + EPS_F);
      scl[r] = sc;
      shf[r] = bn_qkv[512 + ch] - bn_qkv[1024 + ch] * sc;
    }
    if (wr == 0) {
#pragma unroll
      for (int tb = 0; tb < 2; ++tb) {
        int i = 32 * wc + 16 * tb + m;
        U16x4 o;
#pragma unroll
        for (int r = 0; r < 4; ++r) o.u[r] = f2h(cacc[tb][r] * scl[r] + shf[r]);
        *(f16x4*)QKA(i, 4 * h) = o.v;
      }
    } else {
#pragma unroll
      for (int tb = 0; tb < 2; ++tb) {
        int i = 32 * wc + 16 * tb + m;
#pragma unroll
        for (int r = 0; r < 4; ++r)
          *(ushort*)VCA(4 * h + r, i) = f2h(cacc[tb][r] * scl[r] + shf[r]);
      }
    }
  }
  __syncthreads();   // barrier A

  // ---- P1: band-restricted emb GEMM -> dense QE/KE ----
  {
    const int nt = wv;
    const int n = 16 * nt + m;
    f16x4 bqk = *(const f16x4*)QKA(n, 4 * h);
#pragma unroll
    for (int k = 0; k < 5; ++k) {
      int dt = nt + k;
      f16x4 arQ = *(const f16x4*)RQA(16 * dt + m, 4 * h);
      f16x4 arK = *(const f16x4*)RKA(16 * dt + m, 4 * h);
      f32x4 dq = __builtin_amdgcn_mfma_f32_16x16x16f16(arQ, bqk, (f32x4){0.f,0.f,0.f,0.f}, 0, 0, 0);
      f32x4 dk = __builtin_amdgcn_mfma_f32_16x16x16f16(arK, bqk, (f32x4){0.f,0.f,0.f,0.f}, 0, 0, 0);
#pragma unroll
      for (int r = 0; r < 4; ++r) {
        int d = 16 * dt + 4 * h + r;
        int i = n - d + 63;
        if (k == 0 || k == 4) {
          if ((unsigned)i < 64u) {
            *(ushort*)QEA(i, n) = f2h(dq[r]);
            *(ushort*)KEA(i, n) = f2h(dk[r]);
          }
        } else {
          *(ushort*)QEA(i, n) = f2h(dq[r]);
          *(ushort*)KEA(i, n) = f2h(dk[r]);
        }
      }
    }
  }
  __syncthreads();   // barrier B

  // ---- P2: sim ----
  f32x4 acc[4];
#pragma unroll
  for (int tj = 0; tj < 4; ++tj) acc[tj] = (f32x4){0.f, 0.f, 0.f, 0.f};
  {
    const int ia = 16 * wv + m;
    f16x8 af0 = *(const f16x8*)QEA(ia, 8 * h);
    f16x8 af1 = *(const f16x8*)QEA(ia, 32 + 8 * h);
#pragma unroll
    for (int tj = 0; tj < 4; ++tj) {
      int j = 16 * tj + m;
      f16x8 bf0 = *(const f16x8*)KEA(j, 8 * h);
      f16x8 bf1 = *(const f16x8*)KEA(j, 32 + 8 * h);
      acc[tj] = __builtin_amdgcn_mfma_f32_16x16x32_f16(af0, bf0, acc[tj], 0, 0, 0);
      acc[tj] = __builtin_amdgcn_mfma_f32_16x16x32_f16(af1, bf1, acc[tj], 0, 0, 0);
    }
  }

  float s_qk = bn_sim[g]      * rsqrtf(bn_sim[144 + g] + EPS_F);
  float s_qe = bn_sim[16 + g] * rsqrtf(bn_sim[160 + g] + EPS_F);
  float s_ke = bn_sim[32 + g] * rsqrtf(bn_sim[176 + g] + EPS_F);
  float sh   = (bn_sim[48 + g] - bn_sim[96 + g]  * s_qk)
             + (bn_sim[64 + g] - bn_sim[112 + g] * s_qe)
             + (bn_sim[80 + g] - bn_sim[128 + g] * s_ke);

  const int ib = 16 * wv + 4 * h;
  float sv[4][4];
#pragma unroll
  for (int tj = 0; tj < 4; ++tj) {
    int j = 16 * tj + m;
    f16x4 qe4 = *(const f16x4*)QEA(j, ib);
    f16x4 ke4 = *(const f16x4*)KEA(j, ib);
#pragma unroll
    for (int r = 0; r < 4; ++r)
      sv[tj][r] = acc[tj][r] * s_qk + (float)qe4[r] * s_qe + (float)ke4[r] * s_ke + sh;
  }

  // ---- P3: softmax over j ----
  float p[4][4];
  {
    float mx[4];
#pragma unroll
    for (int r = 0; r < 4; ++r) {
      float v = fmaxf(fmaxf(sv[0][r], sv[1][r]), fmaxf(sv[2][r], sv[3][r]));
      v = fmaxf(v, __shfl_xor(v, 1));
      v = fmaxf(v, __shfl_xor(v, 2));
      v = fmaxf(v, __shfl_xor(v, 4));
      v = fmaxf(v, __shfl_xor(v, 8));
      mx[r] = v;
    }
#pragma unroll
    for (int r = 0; r < 4; ++r) {
      float ssum = 0.f;
#pragma unroll
      for (int tj = 0; tj < 4; ++tj) {
        p[tj][r] = __expf(sv[tj][r] - mx[r]);
        ssum += p[tj][r];
      }
      ssum += __shfl_xor(ssum, 1);
      ssum += __shfl_xor(ssum, 2);
      ssum += __shfl_xor(ssum, 4);
      ssum += __shfl_xor(ssum, 8);
      float inv = 1.f / ssum;
#pragma unroll
      for (int tj = 0; tj < 4; ++tj) p[tj][r] *= inv;
    }
  }

  __syncthreads();   // barrier C

  // ---- P4: wave-private zero of A2 rows [16wv,16wv+16), then scatter ----
  {
    uint4 z = make_uint4(0u, 0u, 0u, 0u);
    uint4* base = (uint4*)(smem + wv * 4352);
#pragma unroll
    for (int u = 0; u < 4; ++u) base[lane + 64 * u] = z;
    if (lane < 16) base[lane + 256] = z;
  }
#pragma unroll
  for (int tj = 0; tj < 4; ++tj) {
    int j = 16 * tj + m;
#pragma unroll
    for (int r = 0; r < 4; ++r) {
      int i = ib + r;
      *(ushort*)A2A(i, i - j + 63) = f2h(p[tj][r]);
    }
  }

  // ---- P5: att / att_e ----
  f32x4 accA = (f32x4){0.f, 0.f, 0.f, 0.f};
  f32x4 accE = (f32x4){0.f, 0.f, 0.f, 0.f};
  {
    const int ia = 16 * wv + m;
#pragma unroll
    for (int ks = 0; ks < 2; ++ks) {
      U16x8 pa;
#pragma unroll
      for (int e = 0; e < 8; ++e) {
        int j = 32 * ks + 8 * h + e;
        pa.u[e] = *(ushort*)A2A(ia, ia - j + 63);
      }
      f16x8 vb = *(const f16x8*)VCA(m, 32 * ks + 8 * h);
      accA = __builtin_amdgcn_mfma_f32_16x16x32_f16(pa.v, vb, accA, 0, 0, 0);
    }
#pragma unroll
    for (int ks = 0; ks < 4; ++ks) {
      f16x8 pe = *(const f16x8*)A2A(ia, 32 * ks + 8 * h);
      f16x8 rv = *(const f16x8*)RVA(m, 32 * ks + 8 * h);
      accE = __builtin_amdgcn_mfma_f32_16x16x32_f16(pe, rv, accE, 0, 0, 0);
    }
  }

  // ---- P6: fold bn_out, pixel-major write ----
  {
    int oc = g * 16 + m;
    int c0 = 2 * oc, c1 = c0 + 1;
    float sc0 = bn_out[c0] * rsqrtf(bn_out[1536 + c0] + EPS_F);
    float sh0 = bn_out[512 + c0] - bn_out[1024 + c0] * sc0;
    float sc1 = bn_out[c1] * rsqrtf(bn_out[1536 + c1] + EPS_F);
    float sh1 = bn_out[512 + c1] - bn_out[1024 + c1] * sc1;
    float vv[4];
    vv[0] = accA[0] * sc0 + accE[0] * sc1 + sh0 + sh1;
    vv[1] = accA[1] * sc0 + accE[1] * sc1 + sh0 + sh1;
    vv[2] = accA[2] * sc0 + accE[2] * sc1 + sh0 + sh1;
    vv[3] = accA[3] * sc0 + accE[3] * sc1 + sh0 + sh1;
    size_t base = ((size_t)b * 4096 + (size_t)d1 * 64 + ib) * 256 + oc;
#pragma unroll
    for (int r = 0; r < 4; ++r)
      out16[base + (size_t)r * 256] = f2h(vv[r]);
  }
#undef RQA
#undef RKA
#undef QKA
#undef QEA
#undef KEA
#undef VCA
#undef RVA
#undef A2A
}

extern "C" void kernel_launch(void* const* d_in, const int* in_sizes, int n_in,
                              void* d_out, int out_size, void* d_ws, size_t ws_size,
                              hipStream_t stream) {
  const float* x         = (const float*)d_in[0];
  const float* latent    = (const float*)d_in[1];
  const float* w_in      = (const float*)d_in[2];
  const float* bn_in     = (const float*)d_in[3];
  const float* lin_in    = (const float*)d_in[4];
  const float* alpha_in  = (const float*)d_in[5];
  const float* a0_wqkv   = (const float*)d_in[6];
  const float* a0_bn_qkv = (const float*)d_in[7];
  const float* a0_bn_sim = (const float*)d_in[8];
  const float* a0_bn_out = (const float*)d_in[9];
  const float* a0_rel    = (const float*)d_in[10];
  const float* a1_wqkv   = (const float*)d_in[11];
  const float* a1_bn_qkv = (const float*)d_in[12];
  const float* a1_bn_sim = (const float*)d_in[13];
  const float* a1_bn_out = (const float*)d_in[14];
  const float* a1_rel    = (const float*)d_in[15];
  const float* w_out     = (const float*)d_in[16];
  const float* bn_outp   = (const float*)d_in[17];
  const float* lin_out   = (const float*)d_in[18];
  const float* w_res     = (const float*)d_in[19];
  const float* alpha_fin = (const float*)d_in[20];

  float* ws = (float*)d_ws;
  float* sb_in  = ws;                          // 2048 f
  float* sb_out = ws + 2048;                   // 2048 f
  ushort* w16   = (ushort*)(ws + 4096);        // 393216 u16
  ushort* relimg = w16 + 393216;               // 14336 u16
  ushort* x16   = relimg + 14336;              // 2097152 u16 (b,4096,128)
  ushort* t0    = x16 + 2097152;               // 4194304 u16 (b,4096,256)
  ushort* t1    = t0 + 4194304;                // 4194304 u16 (b,4096,256) ping-pong
  ushort* pool_x = t1 + 4194304;               // 524288 u16  (b,1024,128)

  ushort* w_in16  = w16;
  ushort* a0w16   = w16 + 32768;
  ushort* a1w16   = w16 + 163840;
  ushort* w_out16 = w16 + 294912;
  ushort* w_res16 = w16 + 360448;
  ushort* rimg_a  = relimg;
  ushort* rimg_b  = relimg + 7168;

  // prep: weights/sb/relimg + cvtT(x) + poolx(x)
  prep_kernel<<<2632, 256, 0, stream>>>(w_in, a0_wqkv, a1_wqkv, w_out, w_res,
                                        latent, lin_in, lin_out, a0_rel, a1_rel,
                                        x, w16, relimg, sb_in, sb_out, x16, pool_x);

  // conv_in + cbn + prelu -> t0 (pixel-major, p = h*64+w)
  conv_mfma_kernel<11><<<dim3(32, 4, 4), 256, 0, stream>>>(
      x16, w_in16, t0, 128, 256, 4096, bn_in, sb_in, alpha_in);

  // axial 0 over H (i=h, d1=w), fused qkv conv: t0 -> t1 (out p = w*64+h)
  axial_attn_kernel<<<4096, 256, 0, stream>>>(
      t0, a0w16, a0_bn_qkv, rimg_a, a0_bn_sim, a0_bn_out, t1);

  // axial 1 over W (i=w, d1=h), fused qkv conv: t1 -> t0 (out p = h*64+w, std)
  axial_attn_kernel<<<4096, 256, 0, stream>>>(
      t1, a1w16, a1_bn_qkv, rimg_b, a1_bn_sim, a1_bn_out, t0);

  // fused: pool(t0)@W_out (cbn) + pool_x@W_res, prelu -> d_out (f32 chan-major)
  final_fused_kernel<<<dim3(8, 4, 4), 256, 0, stream>>>(
      t0, pool_x, w_out16, w_res16, (float*)d_out, bn_outp, sb_out, alpha_fin);
}

// Round 16
// 128.634 us; speedup vs baseline: 1.1965x; 1.0246x over previous
//
#include <hip/hip_runtime.h>
#include <hip/hip_bf16.h>

#define EPS_F 1e-5f

typedef __attribute__((ext_vector_type(8))) _Float16 f16x8;
typedef __attribute__((ext_vector_type(4))) _Float16 f16x4;
typedef __attribute__((ext_vector_type(4))) float f32x4;

union U16x8 { ushort u[8]; _Float16 h[8]; f16x8 v; };
union U16x4 { ushort u[4]; f16x4 v; };

static __device__ inline ushort f2h(float f) {
  _Float16 h = (_Float16)f;
  return __builtin_bit_cast(ushort, h);
}
static __device__ inline float h2f(ushort u) {
  return (float)__builtin_bit_cast(_Float16, u);
}

// ---------------- prep: weights->f16, sb, rel images, cvtT(x), poolx(x) ----------------
// grid: [0,1588) weights/sb/relimg ; [1588,2100) cvtT ; [2100,2612) poolx
// relimg per dir (4608 u16): [0,2560) dense relQK [128][20] (c<16 real, else 0);
//                            [2560,4608) RV swizzled image.
__global__ void __launch_bounds__(256) prep_kernel(
    const float* __restrict__ w_in, const float* __restrict__ a0w,
    const float* __restrict__ a1w, const float* __restrict__ w_out,
    const float* __restrict__ w_res,
    const float* __restrict__ latent, const float* __restrict__ lin_in,
    const float* __restrict__ lin_out,
    const float* __restrict__ a0_rel, const float* __restrict__ a1_rel,
    const float* __restrict__ x,
    ushort* __restrict__ w16, ushort* __restrict__ relimg,
    float* __restrict__ sb_in, float* __restrict__ sb_out,
    ushort* __restrict__ x16, ushort* __restrict__ pool_x) {
  const int gid = blockIdx.x;
  const int tid = threadIdx.x;
  __shared__ __align__(16) char lsm[10240];

  if (gid < 1588) {
    int idx = gid * 256 + tid;
    if (idx < 393216) {
      const float* src; int off;
      if (idx < 32768)       { src = w_in;  off = 0; }
      else if (idx < 163840) { src = a0w;   off = 32768; }
      else if (idx < 294912) { src = a1w;   off = 163840; }
      else if (idx < 360448) { src = w_out; off = 294912; }
      else                   { src = w_res; off = 360448; }
      w16[idx] = f2h(src[idx - off]);
    } else if (idx < 397312) {
      int r = idx - 393216;
      int which = r >> 11;
      int rr = r & 2047;
      int b = rr >> 9, k = rr & 511;
      const float* lin = which ? lin_out : lin_in;
      const float* lv = latent + b * 256;
      const float* lr = lin + k * 256;
      float acc = 0.f;
#pragma unroll 8
      for (int l = 0; l < 256; ++l) acc += lv[l] * lr[l];
      (which ? sb_out : sb_in)[b * 512 + k] = acc;
    } else if (idx < 406528) {
      int e = idx - 397312;
      int which = e >= 4608;
      int s = which ? e - 4608 : e;
      const float* rel = which ? a1_rel : a0_rel;
      ushort val = 0;
      if (s < 2560) {                  // dense relQK [128][20], rows c=0..15
        int d = s / 20, c = s % 20;
        if (c < 16 && d < 127) val = f2h(rel[c * 127 + d]);
      } else {                         // RV swizzled image
        int pos = (s - 2560) * 2;
        int c = pos >> 8;
        int inner = (pos & 255) ^ ((c & 7) << 4);
        int d = inner >> 1;
        if (d < 127) val = f2h(rel[(16 + c) * 127 + d]);
      }
      relimg[which * 4608 + s] = val;
    }
  } else if (gid < 2100) {
    // cvtT: x f32 (b,128,4096) -> x16 (b,4096,128)
    int e = gid - 1588;
    int pt = e & 31, ct = (e >> 5) & 3, b = e >> 7;
    ushort (*Lt)[40] = (ushort(*)[40])lsm;
#pragma unroll
    for (int r = 0; r < 16; ++r) {
      int e2 = tid + 256 * r;
      int c = e2 >> 7, p = e2 & 127;
      Lt[p][c] = f2h(x[((size_t)(b * 128 + ct * 32 + c)) * 4096 + pt * 128 + p]);
    }
    __syncthreads();
#pragma unroll
    for (int r = 0; r < 2; ++r) {
      int e2 = tid + 256 * r;
      int p = e2 >> 2, q = e2 & 3;
      *(f16x8*)&x16[((size_t)b * 4096 + pt * 128 + p) * 128 + ct * 32 + 8 * q] =
          *(const f16x8*)&Lt[p][8 * q];
    }
  } else {
    // poolx: x f32 -> pool_x (b,1024,128) f16
    int e = gid - 2100;
    int ip = e & 31, ct = (e >> 5) & 3, b = e >> 7;
    float (*Lp)[33] = (float(*)[33])lsm;
    {
      int c = tid >> 3, grp = tid & 7;
      const float* base = x + ((size_t)(b * 128 + ct * 32 + c)) * 4096 + (2 * ip) * 64 + 8 * grp;
      float4 a0 = *(const float4*)&base[0];
      float4 a1 = *(const float4*)&base[4];
      float4 b0 = *(const float4*)&base[64];
      float4 b1 = *(const float4*)&base[68];
      Lp[c][4 * grp + 0] = 0.25f * (a0.x + a0.y + b0.x + b0.y);
      Lp[c][4 * grp + 1] = 0.25f * (a0.z + a0.w + b0.z + b0.w);
      Lp[c][4 * grp + 2] = 0.25f * (a1.x + a1.y + b1.x + b1.y);
      Lp[c][4 * grp + 3] = 0.25f * (a1.z + a1.w + b1.z + b1.w);
    }
    __syncthreads();
    {
      int jp = tid >> 3, q = tid & 7;
      ushort4 o;
      o.x = f2h(Lp[4 * q + 0][jp]);
      o.y = f2h(Lp[4 * q + 1][jp]);
      o.z = f2h(Lp[4 * q + 2][jp]);
      o.w = f2h(Lp[4 * q + 3][jp]);
      *(ushort4*)&pool_x[((size_t)b * 1024 + ip * 32 + jp) * 128 + ct * 32 + 4 * q] = o;
    }
  }
}

// ---------------- MFMA f16 conv1x1, pixel-major (conv_in only) ----------------
template <int MODE>
__global__ void __launch_bounds__(256) conv_mfma_kernel(
    const ushort* __restrict__ X, const ushort* __restrict__ W16,
    ushort* __restrict__ Y16, int Cin, int Cout, int P,
    const float* __restrict__ bn, const float* __restrict__ sb,
    const float* __restrict__ alpha) {
  const int tid = threadIdx.x;
  const int p0 = blockIdx.x * 128;
  const int o0 = blockIdx.y * 64;
  const int b  = blockIdx.z;
  const int lane = tid & 63;
  const int wv = tid >> 6;
  const int m = lane & 15, h = lane >> 4;
  const int wr = wv >> 1, wc = wv & 1;

  __shared__ __align__(16) char smem[27648];
  ushort (*Xs)[72] = (ushort(*)[72])smem;
  ushort (*Ws)[72] = (ushort(*)[72])(smem + 18432);
  ushort (*Es)[72] = (ushort(*)[72])smem;

  f32x4 acc[2][4];
#pragma unroll
  for (int i = 0; i < 2; ++i)
#pragma unroll
    for (int j = 0; j < 4; ++j) acc[i][j] = (f32x4){0.f, 0.f, 0.f, 0.f};

  const ushort* Xb = X + (size_t)b * P * Cin;

  for (int k0 = 0; k0 < Cin; k0 += 64) {
    __syncthreads();
#pragma unroll
    for (int r = 0; r < 4; ++r) {
      int e = tid + 256 * r;
      int pp = e >> 3, ch = e & 7;
      *(f16x8*)&Xs[pp][8 * ch] =
          *(const f16x8*)&Xb[(size_t)(p0 + pp) * Cin + k0 + 8 * ch];
    }
#pragma unroll
    for (int r = 0; r < 2; ++r) {
      int e = tid + 256 * r;
      int oc = e >> 3, ch = e & 7;
      *(f16x8*)&Ws[oc][8 * ch] =
          *(const f16x8*)&W16[(size_t)(o0 + oc) * Cin + k0 + 8 * ch];
    }
    __syncthreads();
#pragma unroll
    for (int ks = 0; ks < 2; ++ks) {
      f16x8 af[2], bf[4];
#pragma unroll
      for (int t = 0; t < 2; ++t) af[t] = *(const f16x8*)&Ws[32 * wr + 16 * t + m][32 * ks + 8 * h];
#pragma unroll
      for (int t = 0; t < 4; ++t) bf[t] = *(const f16x8*)&Xs[64 * wc + 16 * t + m][32 * ks + 8 * h];
#pragma unroll
      for (int ta = 0; ta < 2; ++ta)
#pragma unroll
        for (int tb = 0; tb < 4; ++tb)
          acc[ta][tb] = __builtin_amdgcn_mfma_f32_16x16x32_f16(af[ta], bf[tb], acc[ta][tb], 0, 0, 0);
    }
  }

  float scl[2][4], shf[2][4];
#pragma unroll
  for (int ta = 0; ta < 2; ++ta)
#pragma unroll
    for (int r = 0; r < 4; ++r) {
      int oc = o0 + 32 * wr + 16 * ta + 4 * h + r;
      float scale = 1.f, shift = 0.f;
      if (MODE & 1) {
        float sc = bn[oc] * rsqrtf(bn[3 * Cout + oc] + EPS_F);
        scale = sc;
        shift = bn[Cout + oc] - bn[2 * Cout + oc] * sc;
      }
      if (MODE & 2) {
        float ss = sb[b * 2 * Cout + oc];
        float bb = sb[b * 2 * Cout + Cout + oc];
        scale *= ss;
        shift = shift * ss + bb;
      }
      scl[ta][r] = scale; shf[ta][r] = shift;
    }
  float al = (MODE & 8) ? *alpha : 0.f;

  __syncthreads();
#pragma unroll
  for (int ta = 0; ta < 2; ++ta)
#pragma unroll
    for (int tb = 0; tb < 4; ++tb)
#pragma unroll
      for (int r = 0; r < 4; ++r) {
        float v = acc[ta][tb][r] * scl[ta][r] + shf[ta][r];
        if (MODE & 8) v = v > 0.f ? v : al * v;
        Es[64 * wc + 16 * tb + m][32 * wr + 16 * ta + 4 * h + r] = f2h(v);
      }
  __syncthreads();
#pragma unroll
  for (int r = 0; r < 4; ++r) {
    int e = tid + 256 * r;
    int pp = e >> 3, q = e & 7;
    *(f16x8*)&Y16[((size_t)b * P + p0 + pp) * Cout + o0 + 8 * q] =
        *(const f16x8*)&Es[pp][8 * q];
  }
}

// ---------------- fused final: pool(t0)·W_out (cbn) + pool_x·W_res, prelu, f32 out ----------------
__global__ void __launch_bounds__(256) final_fused_kernel(
    const ushort* __restrict__ t0, const ushort* __restrict__ pool_x,
    const ushort* __restrict__ Wo, const ushort* __restrict__ Wr,
    float* __restrict__ Y32,
    const float* __restrict__ bn, const float* __restrict__ sb,
    const float* __restrict__ alpha) {
  const int tid = threadIdx.x;
  const int p0 = blockIdx.x * 128;
  const int o0 = blockIdx.y * 64;
  const int b  = blockIdx.z;
  const int lane = tid & 63;
  const int wv = tid >> 6;
  const int m = lane & 15, h = lane >> 4;
  const int wr = wv >> 1, wc = wv & 1;

  __shared__ __align__(16) char smem[27648];
  ushort (*Xs)[72] = (ushort(*)[72])smem;
  ushort (*Ws)[72] = (ushort(*)[72])(smem + 18432);

  f32x4 acc1[2][4], acc2[2][4];
#pragma unroll
  for (int i = 0; i < 2; ++i)
#pragma unroll
    for (int j = 0; j < 4; ++j) {
      acc1[i][j] = (f32x4){0.f, 0.f, 0.f, 0.f};
      acc2[i][j] = (f32x4){0.f, 0.f, 0.f, 0.f};
    }

  // phase A: pooled t0 (Cin=256) @ W_out -> acc1
  for (int k0 = 0; k0 < 256; k0 += 64) {
    __syncthreads();
#pragma unroll
    for (int r = 0; r < 4; ++r) {
      int e = tid + 256 * r;
      int pp = e >> 3, ch = e & 7;
      int pg = p0 + pp;
      int ip = pg >> 5, jp = pg & 31;
      size_t tb = ((size_t)b * 4096 + ip * 128 + jp * 2) * 256 + k0 + 8 * ch;
      U16x8 a, bb, c, d, o;
      a.v  = *(const f16x8*)&t0[tb];
      bb.v = *(const f16x8*)&t0[tb + 256];
      c.v  = *(const f16x8*)&t0[tb + 64 * 256];
      d.v  = *(const f16x8*)&t0[tb + 65 * 256];
#pragma unroll
      for (int e2 = 0; e2 < 8; ++e2)
        o.h[e2] = ((a.h[e2] + bb.h[e2]) + (c.h[e2] + d.h[e2])) * (_Float16)0.25f;
      *(f16x8*)&Xs[pp][8 * ch] = o.v;
    }
#pragma unroll
    for (int r = 0; r < 2; ++r) {
      int e = tid + 256 * r;
      int oc = e >> 3, ch = e & 7;
      *(f16x8*)&Ws[oc][8 * ch] = *(const f16x8*)&Wo[(size_t)(o0 + oc) * 256 + k0 + 8 * ch];
    }
    __syncthreads();
#pragma unroll
    for (int ks = 0; ks < 2; ++ks) {
      f16x8 af[2], bf[4];
#pragma unroll
      for (int t = 0; t < 2; ++t) af[t] = *(const f16x8*)&Ws[32 * wr + 16 * t + m][32 * ks + 8 * h];
#pragma unroll
      for (int t = 0; t < 4; ++t) bf[t] = *(const f16x8*)&Xs[64 * wc + 16 * t + m][32 * ks + 8 * h];
#pragma unroll
      for (int ta = 0; ta < 2; ++ta)
#pragma unroll
        for (int tb2 = 0; tb2 < 4; ++tb2)
          acc1[ta][tb2] = __builtin_amdgcn_mfma_f32_16x16x32_f16(af[ta], bf[tb2], acc1[ta][tb2], 0, 0, 0);
    }
  }

  // phase B: pool_x (Cin=128) @ W_res -> acc2
  for (int k0 = 0; k0 < 128; k0 += 64) {
    __syncthreads();
#pragma unroll
    for (int r = 0; r < 4; ++r) {
      int e = tid + 256 * r;
      int pp = e >> 3, ch = e & 7;
      *(f16x8*)&Xs[pp][8 * ch] =
          *(const f16x8*)&pool_x[((size_t)b * 1024 + p0 + pp) * 128 + k0 + 8 * ch];
    }
#pragma unroll
    for (int r = 0; r < 2; ++r) {
      int e = tid + 256 * r;
      int oc = e >> 3, ch = e & 7;
      *(f16x8*)&Ws[oc][8 * ch] = *(const f16x8*)&Wr[(size_t)(o0 + oc) * 128 + k0 + 8 * ch];
    }
    __syncthreads();
#pragma unroll
    for (int ks = 0; ks < 2; ++ks) {
      f16x8 af[2], bf[4];
#pragma unroll
      for (int t = 0; t < 2; ++t) af[t] = *(const f16x8*)&Ws[32 * wr + 16 * t + m][32 * ks + 8 * h];
#pragma unroll
      for (int t = 0; t < 4; ++t) bf[t] = *(const f16x8*)&Xs[64 * wc + 16 * t + m][32 * ks + 8 * h];
#pragma unroll
      for (int ta = 0; ta < 2; ++ta)
#pragma unroll
        for (int tb2 = 0; tb2 < 4; ++tb2)
          acc2[ta][tb2] = __builtin_amdgcn_mfma_f32_16x16x32_f16(af[ta], bf[tb2], acc2[ta][tb2], 0, 0, 0);
    }
  }

  const float al = *alpha;
#pragma unroll
  for (int ta = 0; ta < 2; ++ta)
#pragma unroll
    for (int r = 0; r < 4; ++r) {
      int oc = o0 + 32 * wr + 16 * ta + 4 * h + r;
      float sc = bn[oc] * rsqrtf(bn[768 + oc] + EPS_F);
      float shift = bn[256 + oc] - bn[512 + oc] * sc;
      float ss = sb[b * 512 + oc];
      float bb = sb[b * 512 + 256 + oc];
      float scale = sc * ss;
      shift = shift * ss + bb;
#pragma unroll
      for (int tb2 = 0; tb2 < 4; ++tb2) {
        int p = p0 + 64 * wc + 16 * tb2 + m;
        float v = acc1[ta][tb2][r] * scale + shift + acc2[ta][tb2][r];
        v = v > 0.f ? v : al * v;
        Y32[((size_t)b * 256 + oc) * 1024 + p] = v;
      }
    }
}

// ---------------- axial attention + fused qkv conv, 32 KB LDS (5 blocks/CU) ----------------
// Input tin (b, p, 256) with p = i*64 + d1. Output tout (b, p', 256), p' = d1*64 + i.
__global__ void __launch_bounds__(256) axial_attn_kernel(
    const ushort* __restrict__ t0in, const ushort* __restrict__ wqkv,
    const float* __restrict__ bn_qkv,
    const ushort* __restrict__ relimg,
    const float* __restrict__ bn_sim, const float* __restrict__ bn_out,
    ushort* __restrict__ out16) {
  const int tid = threadIdx.x;
  int lin = blockIdx.x;                       // bijective XCD swizzle, bd-major chunks
  int wg = ((lin & 7) << 9) + (lin >> 3);
  const int g  = wg & 15;
  const int bd = wg >> 4;
  const int b  = bd >> 6;
  const int d1 = bd & 63;

  __shared__ __align__(16) char smem[32768];
  // relQK [128][20] @0 (rows c=0..15 real) 5120 | QK [64][24] @5120 3072
  // QE [64][72] @8192 9216 (= C0 buf0) | KE @17408 9216 (= buf1)
  // VC swz @26624 2048 | RV swz @28672 4096  -> total 32768
  // A2 [64][136] @0 overlay = 17408 B = relQK+QK+QE exactly
#define RAA(d, c)  (smem + (d) * 40 + (c) * 2)
#define QKA(i, c)  (smem + 5120 + (i) * 48 + (c) * 2)
#define QEA(i, k)  (smem + 8192 + (i) * 144 + (k) * 2)
#define KEA(j, k)  (smem + 17408 + (j) * 144 + (k) * 2)
#define VCA(c, j)  (smem + 26624 + ((((c) * 128 + (j) * 2)) ^ (((c) & 7) << 4)))
#define RVA(c, d)  (smem + 28672 + ((((c) * 256 + (d) * 2)) ^ (((c) & 7) << 4)))
#define A2A(i, d)  (smem + (i) * 272 + (d) * 2)

  const int lane = tid & 63;
  const int wv   = tid >> 6;
  const int m    = lane & 15;
  const int h    = lane >> 4;
  const int wr   = wv >> 1, wc = wv & 1;

  // ---- P0: copy rel images (relQK 320 uint4, RV 256 uint4) ----
  {
    const uint4* img = (const uint4*)relimg;
    ((uint4*)smem)[tid] = img[tid];
    if (tid < 64) ((uint4*)smem)[256 + tid] = img[256 + tid];
    ((uint4*)(smem + 28672))[tid] = img[320 + tid];
  }

  // ---- C0: fused qkv conv, double-buffered LDS staging (buf0=QE, buf1=KE) ----
  f32x4 cacc[2];
  cacc[0] = (f32x4){0.f, 0.f, 0.f, 0.f};
  cacc[1] = (f32x4){0.f, 0.f, 0.f, 0.f};
  {
    const ushort* Xb = t0in + ((size_t)b * 4096 + d1) * 256;
    const ushort* Wg = wqkv + ((size_t)(g * 32 + 16 * wr + m)) * 256;
    char* const XS0 = smem + 8192;
    char* const XS1 = smem + 17408;
    const int si = tid >> 3, ssub = tid & 7;
#pragma unroll
    for (int r = 0; r < 2; ++r) {
      int i = si + 32 * r;
      *(f16x8*)(XS0 + i * 144 + ssub * 16) =
          *(const f16x8*)&Xb[(size_t)i * 16384 + 8 * ssub];
    }
    __syncthreads();
#pragma unroll
    for (int c = 0; c < 4; ++c) {
      char* cur = (c & 1) ? XS1 : XS0;
      if (c < 3) {
        char* nxt = (c & 1) ? XS0 : XS1;
#pragma unroll
        for (int r = 0; r < 2; ++r) {
          int i = si + 32 * r;
          *(f16x8*)(nxt + i * 144 + ssub * 16) =
              *(const f16x8*)&Xb[(size_t)i * 16384 + (c + 1) * 64 + 8 * ssub];
        }
      }
#pragma unroll
      for (int ks = 0; ks < 2; ++ks) {
        f16x8 af = *(const f16x8*)&Wg[c * 64 + 32 * ks + 8 * h];
#pragma unroll
        for (int tb = 0; tb < 2; ++tb) {
          int i = 32 * wc + 16 * tb + m;
          f16x8 bf = *(const f16x8*)(cur + i * 144 + (32 * ks + 8 * h) * 2);
          cacc[tb] = __builtin_amdgcn_mfma_f32_16x16x32_f16(af, bf, cacc[tb], 0, 0, 0);
        }
      }
      __syncthreads();
    }
  }
  // C1: epilogue — fold bn_qkv, write QK (wr=0) / VC (wr=1)
  {
    float scl[4], shf[4];
#pragma unroll
    for (int r = 0; r < 4; ++r) {
      int ch = g * 32 + 16 * wr + 4 * h + r;
      float sc = bn_qkv[ch] * rsqrtf(bn_qkv[1536 + ch] + EPS_F);
      scl[r] = sc;
      shf[r] = bn_qkv[512 + ch] - bn_qkv[1024 + ch] * sc;
    }
    if (wr == 0) {
#pragma unroll
      for (int tb = 0; tb < 2; ++tb) {
        int i = 32 * wc + 16 * tb + m;
        U16x4 o;
#pragma unroll
        for (int r = 0; r < 4; ++r) o.u[r] = f2h(cacc[tb][r] * scl[r] + shf[r]);
        *(f16x4*)QKA(i, 4 * h) = o.v;
      }
    } else {
#pragma unroll
      for (int tb = 0; tb < 2; ++tb) {
        int i = 32 * wc + 16 * tb + m;
#pragma unroll
        for (int r = 0; r < 4; ++r)
          *(ushort*)VCA(4 * h + r, i) = f2h(cacc[tb][r] * scl[r] + shf[r]);
      }
    }
  }
  __syncthreads();   // barrier A

  // ---- P1: band-restricted emb GEMM (zeros injected in registers) ----
  {
    const int nt = wv;
    const int n = 16 * nt + m;
    f16x4 bqk = *(const f16x4*)QKA(n, 4 * h);
    const f16x4 z4 = (f16x4){(_Float16)0.f, (_Float16)0.f, (_Float16)0.f, (_Float16)0.f};
    const bool qside = (h < 2);
#pragma unroll
    for (int k = 0; k < 5; ++k) {
      int dt = nt + k;
      f16x4 ar = *(const f16x4*)RAA(16 * dt + m, 4 * h);
      f16x4 arQ = qside ? ar : z4;
      f16x4 arK = qside ? z4 : ar;
      f32x4 dq = __builtin_amdgcn_mfma_f32_16x16x16f16(arQ, bqk, (f32x4){0.f,0.f,0.f,0.f}, 0, 0, 0);
      f32x4 dk = __builtin_amdgcn_mfma_f32_16x16x16f16(arK, bqk, (f32x4){0.f,0.f,0.f,0.f}, 0, 0, 0);
#pragma unroll
      for (int r = 0; r < 4; ++r) {
        int d = 16 * dt + 4 * h + r;
        int i = n - d + 63;
        if (k == 0 || k == 4) {
          if ((unsigned)i < 64u) {
            *(ushort*)QEA(i, n) = f2h(dq[r]);
            *(ushort*)KEA(i, n) = f2h(dk[r]);
          }
        } else {
          *(ushort*)QEA(i, n) = f2h(dq[r]);
          *(ushort*)KEA(i, n) = f2h(dk[r]);
        }
      }
    }
  }
  __syncthreads();   // barrier B

  // ---- P2: sim ----
  f32x4 acc[4];
#pragma unroll
  for (int tj = 0; tj < 4; ++tj) acc[tj] = (f32x4){0.f, 0.f, 0.f, 0.f};
  {
    const int ia = 16 * wv + m;
    f16x8 af0 = *(const f16x8*)QEA(ia, 8 * h);
    f16x8 af1 = *(const f16x8*)QEA(ia, 32 + 8 * h);
#pragma unroll
    for (int tj = 0; tj < 4; ++tj) {
      int j = 16 * tj + m;
      f16x8 bf0 = *(const f16x8*)KEA(j, 8 * h);
      f16x8 bf1 = *(const f16x8*)KEA(j, 32 + 8 * h);
      acc[tj] = __builtin_amdgcn_mfma_f32_16x16x32_f16(af0, bf0, acc[tj], 0, 0, 0);
      acc[tj] = __builtin_amdgcn_mfma_f32_16x16x32_f16(af1, bf1, acc[tj], 0, 0, 0);
    }
  }

  float s_qk = bn_sim[g]      * rsqrtf(bn_sim[144 + g] + EPS_F);
  float s_qe = bn_sim[16 + g] * rsqrtf(bn_sim[160 + g] + EPS_F);
  float s_ke = bn_sim[32 + g] * rsqrtf(bn_sim[176 + g] + EPS_F);
  float sh   = (bn_sim[48 + g] - bn_sim[96 + g]  * s_qk)
             + (bn_sim[64 + g] - bn_sim[112 + g] * s_qe)
             + (bn_sim[80 + g] - bn_sim[128 + g] * s_ke);

  const int ib = 16 * wv + 4 * h;
  float sv[4][4];
#pragma unroll
  for (int tj = 0; tj < 4; ++tj) {
    int j = 16 * tj + m;
    f16x4 qe4 = *(const f16x4*)QEA(j, ib);
    f16x4 ke4 = *(const f16x4*)KEA(j, ib);
#pragma unroll
    for (int r = 0; r < 4; ++r)
      sv[tj][r] = acc[tj][r] * s_qk + (float)qe4[r] * s_qe + (float)ke4[r] * s_ke + sh;
  }

  // ---- P3: softmax over j ----
  float p[4][4];
  {
    float mx[4];
#pragma unroll
    for (int r = 0; r < 4; ++r) {
      float v = fmaxf(fmaxf(sv[0][r], sv[1][r]), fmaxf(sv[2][r], sv[3][r]));
      v = fmaxf(v, __shfl_xor(v, 1));
      v = fmaxf(v, __shfl_xor(v, 2));
      v = fmaxf(v, __shfl_xor(v, 4));
      v = fmaxf(v, __shfl_xor(v, 8));
      mx[r] = v;
    }
#pragma unroll
    for (int r = 0; r < 4; ++r) {
      float ssum = 0.f;
#pragma unroll
      for (int tj = 0; tj < 4; ++tj) {
        p[tj][r] = __expf(sv[tj][r] - mx[r]);
        ssum += p[tj][r];
      }
      ssum += __shfl_xor(ssum, 1);
      ssum += __shfl_xor(ssum, 2);
      ssum += __shfl_xor(ssum, 4);
      ssum += __shfl_xor(ssum, 8);
      float inv = 1.f / ssum;
#pragma unroll
      for (int tj = 0; tj < 4; ++tj) p[tj][r] *= inv;
    }
  }

  __syncthreads();   // barrier C

  // ---- P4: wave-private zero of A2 rows [16wv,16wv+16), then scatter ----
  {
    uint4 z = make_uint4(0u, 0u, 0u, 0u);
    uint4* base = (uint4*)(smem + wv * 4352);
#pragma unroll
    for (int u = 0; u < 4; ++u) base[lane + 64 * u] = z;
    if (lane < 16) base[lane + 256] = z;
  }
#pragma unroll
  for (int tj = 0; tj < 4; ++tj) {
    int j = 16 * tj + m;
#pragma unroll
    for (int r = 0; r < 4; ++r) {
      int i = ib + r;
      *(ushort*)A2A(i, i - j + 63) = f2h(p[tj][r]);
    }
  }

  // ---- P5: att / att_e ----
  f32x4 accA = (f32x4){0.f, 0.f, 0.f, 0.f};
  f32x4 accE = (f32x4){0.f, 0.f, 0.f, 0.f};
  {
    const int ia = 16 * wv + m;
#pragma unroll
    for (int ks = 0; ks < 2; ++ks) {
      U16x8 pa;
#pragma unroll
      for (int e = 0; e < 8; ++e) {
        int j = 32 * ks + 8 * h + e;
        pa.u[e] = *(ushort*)A2A(ia, ia - j + 63);
      }
      f16x8 vb = *(const f16x8*)VCA(m, 32 * ks + 8 * h);
      accA = __builtin_amdgcn_mfma_f32_16x16x32_f16(pa.v, vb, accA, 0, 0, 0);
    }
#pragma unroll
    for (int ks = 0; ks < 4; ++ks) {
      f16x8 pe = *(const f16x8*)A2A(ia, 32 * ks + 8 * h);
      f16x8 rv = *(const f16x8*)RVA(m, 32 * ks + 8 * h);
      accE = __builtin_amdgcn_mfma_f32_16x16x32_f16(pe, rv, accE, 0, 0, 0);
    }
  }

  // ---- P6: fold bn_out, pixel-major write ----
  {
    int oc = g * 16 + m;
    int c0 = 2 * oc, c1 = c0 + 1;
    float sc0 = bn_out[c0] * rsqrtf(bn_out[1536 + c0] + EPS_F);
    float sh0 = bn_out[512 + c0] - bn_out[1024 + c0] * sc0;
    float sc1 = bn_out[c1] * rsqrtf(bn_out[1536 + c1] + EPS_F);
    float sh1 = bn_out[512 + c1] - bn_out[1024 + c1] * sc1;
    float vv[4];
    vv[0] = accA[0] * sc0 + accE[0] * sc1 + sh0 + sh1;
    vv[1] = accA[1] * sc0 + accE[1] * sc1 + sh0 + sh1;
    vv[2] = accA[2] * sc0 + accE[2] * sc1 + sh0 + sh1;
    vv[3] = accA[3] * sc0 + accE[3] * sc1 + sh0 + sh1;
    size_t base = ((size_t)b * 4096 + (size_t)d1 * 64 + ib) * 256 + oc;
#pragma unroll
    for (int r = 0; r < 4; ++r)
      out16[base + (size_t)r * 256] = f2h(vv[r]);
  }
#undef RAA
#undef QKA
#undef QEA
#undef KEA
#undef VCA
#undef RVA
#undef A2A
}

extern "C" void kernel_launch(void* const* d_in, const int* in_sizes, int n_in,
                              void* d_out, int out_size, void* d_ws, size_t ws_size,
                              hipStream_t stream) {
  const float* x         = (const float*)d_in[0];
  const float* latent    = (const float*)d_in[1];
  const float* w_in      = (const float*)d_in[2];
  const float* bn_in     = (const float*)d_in[3];
  const float* lin_in    = (const float*)d_in[4];
  const float* alpha_in  = (const float*)d_in[5];
  const float* a0_wqkv   = (const float*)d_in[6];
  const float* a0_bn_qkv = (const float*)d_in[7];
  const float* a0_bn_sim = (const float*)d_in[8];
  const float* a0_bn_out = (const float*)d_in[9];
  const float* a0_rel    = (const float*)d_in[10];
  const float* a1_wqkv   = (const float*)d_in[11];
  const float* a1_bn_qkv = (const float*)d_in[12];
  const float* a1_bn_sim = (const float*)d_in[13];
  const float* a1_bn_out = (const float*)d_in[14];
  const float* a1_rel    = (const float*)d_in[15];
  const float* w_out     = (const float*)d_in[16];
  const float* bn_outp   = (const float*)d_in[17];
  const float* lin_out   = (const float*)d_in[18];
  const float* w_res     = (const float*)d_in[19];
  const float* alpha_fin = (const float*)d_in[20];

  float* ws = (float*)d_ws;
  float* sb_in  = ws;                          // 2048 f
  float* sb_out = ws + 2048;                   // 2048 f
  ushort* w16   = (ushort*)(ws + 4096);        // 393216 u16
  ushort* relimg = w16 + 393216;               // 9216 u16 (2 x 4608)
  ushort* x16   = relimg + 9216;               // 2097152 u16 (b,4096,128)
  ushort* t0    = x16 + 2097152;               // 4194304 u16 (b,4096,256)
  ushort* t1    = t0 + 4194304;                // 4194304 u16 ping-pong
  ushort* pool_x = t1 + 4194304;               // 524288 u16  (b,1024,128)

  ushort* w_in16  = w16;
  ushort* a0w16   = w16 + 32768;
  ushort* a1w16   = w16 + 163840;
  ushort* w_out16 = w16 + 294912;
  ushort* w_res16 = w16 + 360448;
  ushort* rimg_a  = relimg;
  ushort* rimg_b  = relimg + 4608;

  // prep: weights/sb/relimg + cvtT(x) + poolx(x)
  prep_kernel<<<2612, 256, 0, stream>>>(w_in, a0_wqkv, a1_wqkv, w_out, w_res,
                                        latent, lin_in, lin_out, a0_rel, a1_rel,
                                        x, w16, relimg, sb_in, sb_out, x16, pool_x);

  // conv_in + cbn + prelu -> t0 (pixel-major, p = h*64+w)
  conv_mfma_kernel<11><<<dim3(32, 4, 4), 256, 0, stream>>>(
      x16, w_in16, t0, 128, 256, 4096, bn_in, sb_in, alpha_in);

  // axial 0 over H (i=h, d1=w), fused qkv conv: t0 -> t1 (out p = w*64+h)
  axial_attn_kernel<<<4096, 256, 0, stream>>>(
      t0, a0w16, a0_bn_qkv, rimg_a, a0_bn_sim, a0_bn_out, t1);

  // axial 1 over W (i=w, d1=h), fused qkv conv: t1 -> t0 (out p = h*64+w, std)
  axial_attn_kernel<<<4096, 256, 0, stream>>>(
      t1, a1w16, a1_bn_qkv, rimg_b, a1_bn_sim, a1_bn_out, t0);

  // fused: pool(t0)@W_out (cbn) + pool_x@W_res, prelu -> d_out (f32 chan-major)
  final_fused_kernel<<<dim3(8, 4, 4), 256, 0, stream>>>(
      t0, pool_x, w_out16, w_res16, (float*)d_out, bn_outp, sb_out, alpha_fin);
}

// Round 17
// 120.397 us; speedup vs baseline: 1.2784x; 1.0684x over previous
//
#include <hip/hip_runtime.h>
#include <hip/hip_bf16.h>

#define EPS_F 1e-5f

typedef __attribute__((ext_vector_type(8))) _Float16 f16x8;
typedef __attribute__((ext_vector_type(4))) _Float16 f16x4;
typedef __attribute__((ext_vector_type(4))) float f32x4;

union U16x8 { ushort u[8]; _Float16 h[8]; f16x8 v; };
union U16x4 { ushort u[4]; f16x4 v; };

static __device__ inline ushort f2h(float f) {
  _Float16 h = (_Float16)f;
  return __builtin_bit_cast(ushort, h);
}
static __device__ inline float h2f(ushort u) {
  return (float)__builtin_bit_cast(_Float16, u);
}

// ---------------- prep: weights->f16, sb, rel images, cvtT(x), poolx(x) ----------------
// grid: [0,1588) weights/sb/relimg ; [1588,2100) cvtT ; [2100,2612) poolx
__global__ void __launch_bounds__(256) prep_kernel(
    const float* __restrict__ w_in, const float* __restrict__ a0w,
    const float* __restrict__ a1w, const float* __restrict__ w_out,
    const float* __restrict__ w_res,
    const float* __restrict__ latent, const float* __restrict__ lin_in,
    const float* __restrict__ lin_out,
    const float* __restrict__ a0_rel, const float* __restrict__ a1_rel,
    const float* __restrict__ x,
    ushort* __restrict__ w16, ushort* __restrict__ relimg,
    float* __restrict__ sb_in, float* __restrict__ sb_out,
    ushort* __restrict__ x16, ushort* __restrict__ pool_x) {
  const int gid = blockIdx.x;
  const int tid = threadIdx.x;
  __shared__ __align__(16) char lsm[10240];

  if (gid < 1588) {
    int idx = gid * 256 + tid;
    if (idx < 393216) {
      const float* src; int off;
      if (idx < 32768)       { src = w_in;  off = 0; }
      else if (idx < 163840) { src = a0w;   off = 32768; }
      else if (idx < 294912) { src = a1w;   off = 163840; }
      else if (idx < 360448) { src = w_out; off = 294912; }
      else                   { src = w_res; off = 360448; }
      w16[idx] = f2h(src[idx - off]);
    } else if (idx < 397312) {
      int r = idx - 393216;
      int which = r >> 11;
      int rr = r & 2047;
      int b = rr >> 9, k = rr & 511;
      const float* lin = which ? lin_out : lin_in;
      const float* lv = latent + b * 256;
      const float* lr = lin + k * 256;
      float acc = 0.f;
#pragma unroll 8
      for (int l = 0; l < 256; ++l) acc += lv[l] * lr[l];
      (which ? sb_out : sb_in)[b * 512 + k] = acc;
    } else if (idx < 406528) {
      int e = idx - 397312;
      int which = e >= 4608;
      int s = which ? e - 4608 : e;
      const float* rel = which ? a1_rel : a0_rel;
      ushort val = 0;
      if (s < 2560) {                  // dense relQK [128][20], rows c=0..15
        int d = s / 20, c = s % 20;
        if (c < 16 && d < 127) val = f2h(rel[c * 127 + d]);
      } else {                         // RV swizzled image
        int pos = (s - 2560) * 2;
        int c = pos >> 8;
        int inner = (pos & 255) ^ ((c & 7) << 4);
        int d = inner >> 1;
        if (d < 127) val = f2h(rel[(16 + c) * 127 + d]);
      }
      relimg[which * 4608 + s] = val;
    }
  } else if (gid < 2100) {
    // cvtT: x f32 (b,128,4096) -> x16 (b,4096,128)
    int e = gid - 1588;
    int pt = e & 31, ct = (e >> 5) & 3, b = e >> 7;
    ushort (*Lt)[40] = (ushort(*)[40])lsm;
#pragma unroll
    for (int r = 0; r < 16; ++r) {
      int e2 = tid + 256 * r;
      int c = e2 >> 7, p = e2 & 127;
      Lt[p][c] = f2h(x[((size_t)(b * 128 + ct * 32 + c)) * 4096 + pt * 128 + p]);
    }
    __syncthreads();
#pragma unroll
    for (int r = 0; r < 2; ++r) {
      int e2 = tid + 256 * r;
      int p = e2 >> 2, q = e2 & 3;
      *(f16x8*)&x16[((size_t)b * 4096 + pt * 128 + p) * 128 + ct * 32 + 8 * q] =
          *(const f16x8*)&Lt[p][8 * q];
    }
  } else {
    // poolx: x f32 -> pool_x (b,1024,128) f16
    int e = gid - 2100;
    int ip = e & 31, ct = (e >> 5) & 3, b = e >> 7;
    float (*Lp)[33] = (float(*)[33])lsm;
    {
      int c = tid >> 3, grp = tid & 7;
      const float* base = x + ((size_t)(b * 128 + ct * 32 + c)) * 4096 + (2 * ip) * 64 + 8 * grp;
      float4 a0 = *(const float4*)&base[0];
      float4 a1 = *(const float4*)&base[4];
      float4 b0 = *(const float4*)&base[64];
      float4 b1 = *(const float4*)&base[68];
      Lp[c][4 * grp + 0] = 0.25f * (a0.x + a0.y + b0.x + b0.y);
      Lp[c][4 * grp + 1] = 0.25f * (a0.z + a0.w + b0.z + b0.w);
      Lp[c][4 * grp + 2] = 0.25f * (a1.x + a1.y + b1.x + b1.y);
      Lp[c][4 * grp + 3] = 0.25f * (a1.z + a1.w + b1.z + b1.w);
    }
    __syncthreads();
    {
      int jp = tid >> 3, q = tid & 7;
      ushort4 o;
      o.x = f2h(Lp[4 * q + 0][jp]);
      o.y = f2h(Lp[4 * q + 1][jp]);
      o.z = f2h(Lp[4 * q + 2][jp]);
      o.w = f2h(Lp[4 * q + 3][jp]);
      *(ushort4*)&pool_x[((size_t)b * 1024 + ip * 32 + jp) * 128 + ct * 32 + 4 * q] = o;
    }
  }
}

// ---------------- MFMA f16 conv1x1, pixel-major, BM=64 x BN=64 (conv_in) ----------------
template <int MODE>
__global__ void __launch_bounds__(256) conv_mfma_kernel(
    const ushort* __restrict__ X, const ushort* __restrict__ W16,
    ushort* __restrict__ Y16, int Cin, int Cout, int P,
    const float* __restrict__ bn, const float* __restrict__ sb,
    const float* __restrict__ alpha) {
  const int tid = threadIdx.x;
  const int p0 = blockIdx.x * 64;
  const int o0 = blockIdx.y * 64;
  const int b  = blockIdx.z;
  const int lane = tid & 63;
  const int wv = tid >> 6;
  const int m = lane & 15, h = lane >> 4;
  const int wr = wv >> 1, wc = wv & 1;

  __shared__ __align__(16) char smem[18432];
  ushort (*Xs)[72] = (ushort(*)[72])smem;             // [64][72]
  ushort (*Ws)[72] = (ushort(*)[72])(smem + 9216);    // [64][72]
  ushort (*Es)[72] = (ushort(*)[72])smem;             // epilogue overlay

  f32x4 acc[2][2];
#pragma unroll
  for (int i = 0; i < 2; ++i)
#pragma unroll
    for (int j = 0; j < 2; ++j) acc[i][j] = (f32x4){0.f, 0.f, 0.f, 0.f};

  const ushort* Xb = X + (size_t)b * P * Cin;

  for (int k0 = 0; k0 < Cin; k0 += 64) {
    __syncthreads();
#pragma unroll
    for (int r = 0; r < 2; ++r) {
      int e = tid + 256 * r;
      int pp = e >> 3, ch = e & 7;
      *(f16x8*)&Xs[pp][8 * ch] =
          *(const f16x8*)&Xb[(size_t)(p0 + pp) * Cin + k0 + 8 * ch];
    }
#pragma unroll
    for (int r = 0; r < 2; ++r) {
      int e = tid + 256 * r;
      int oc = e >> 3, ch = e & 7;
      *(f16x8*)&Ws[oc][8 * ch] =
          *(const f16x8*)&W16[(size_t)(o0 + oc) * Cin + k0 + 8 * ch];
    }
    __syncthreads();
#pragma unroll
    for (int ks = 0; ks < 2; ++ks) {
      f16x8 af[2], bf[2];
#pragma unroll
      for (int t = 0; t < 2; ++t) af[t] = *(const f16x8*)&Ws[32 * wr + 16 * t + m][32 * ks + 8 * h];
#pragma unroll
      for (int t = 0; t < 2; ++t) bf[t] = *(const f16x8*)&Xs[32 * wc + 16 * t + m][32 * ks + 8 * h];
#pragma unroll
      for (int ta = 0; ta < 2; ++ta)
#pragma unroll
        for (int tb = 0; tb < 2; ++tb)
          acc[ta][tb] = __builtin_amdgcn_mfma_f32_16x16x32_f16(af[ta], bf[tb], acc[ta][tb], 0, 0, 0);
    }
  }

  float scl[2][4], shf[2][4];
#pragma unroll
  for (int ta = 0; ta < 2; ++ta)
#pragma unroll
    for (int r = 0; r < 4; ++r) {
      int oc = o0 + 32 * wr + 16 * ta + 4 * h + r;
      float scale = 1.f, shift = 0.f;
      if (MODE & 1) {
        float sc = bn[oc] * rsqrtf(bn[3 * Cout + oc] + EPS_F);
        scale = sc;
        shift = bn[Cout + oc] - bn[2 * Cout + oc] * sc;
      }
      if (MODE & 2) {
        float ss = sb[b * 2 * Cout + oc];
        float bb = sb[b * 2 * Cout + Cout + oc];
        scale *= ss;
        shift = shift * ss + bb;
      }
      scl[ta][r] = scale; shf[ta][r] = shift;
    }
  float al = (MODE & 8) ? *alpha : 0.f;

  __syncthreads();
#pragma unroll
  for (int ta = 0; ta < 2; ++ta)
#pragma unroll
    for (int tb = 0; tb < 2; ++tb)
#pragma unroll
      for (int r = 0; r < 4; ++r) {
        float v = acc[ta][tb][r] * scl[ta][r] + shf[ta][r];
        if (MODE & 8) v = v > 0.f ? v : al * v;
        Es[32 * wc + 16 * tb + m][32 * wr + 16 * ta + 4 * h + r] = f2h(v);
      }
  __syncthreads();
#pragma unroll
  for (int r = 0; r < 2; ++r) {
    int e = tid + 256 * r;
    int pp = e >> 3, q = e & 7;
    *(f16x8*)&Y16[((size_t)b * P + p0 + pp) * Cout + o0 + 8 * q] =
        *(const f16x8*)&Es[pp][8 * q];
  }
}

// ---------------- fused final: pool(t0)·W_out (cbn) + pool_x·W_res, BN=64 ----------------
// grid (16, 4, 4). Output d_out (b,256,1024) f32 chan-major.
__global__ void __launch_bounds__(256) final_fused_kernel(
    const ushort* __restrict__ t0, const ushort* __restrict__ pool_x,
    const ushort* __restrict__ Wo, const ushort* __restrict__ Wr,
    float* __restrict__ Y32,
    const float* __restrict__ bn, const float* __restrict__ sb,
    const float* __restrict__ alpha) {
  const int tid = threadIdx.x;
  const int p0 = blockIdx.x * 64;
  const int o0 = blockIdx.y * 64;
  const int b  = blockIdx.z;
  const int lane = tid & 63;
  const int wv = tid >> 6;
  const int m = lane & 15, h = lane >> 4;
  const int wr = wv >> 1, wc = wv & 1;

  __shared__ __align__(16) char smem[18432];
  ushort (*Xs)[72] = (ushort(*)[72])smem;
  ushort (*Ws)[72] = (ushort(*)[72])(smem + 9216);

  f32x4 acc1[2][2], acc2[2][2];
#pragma unroll
  for (int i = 0; i < 2; ++i)
#pragma unroll
    for (int j = 0; j < 2; ++j) {
      acc1[i][j] = (f32x4){0.f, 0.f, 0.f, 0.f};
      acc2[i][j] = (f32x4){0.f, 0.f, 0.f, 0.f};
    }

  // phase A: pooled t0 (Cin=256) @ W_out -> acc1
  for (int k0 = 0; k0 < 256; k0 += 64) {
    __syncthreads();
#pragma unroll
    for (int r = 0; r < 2; ++r) {
      int e = tid + 256 * r;
      int pp = e >> 3, ch = e & 7;
      int pg = p0 + pp;
      int ip = pg >> 5, jp = pg & 31;
      size_t tb = ((size_t)b * 4096 + ip * 128 + jp * 2) * 256 + k0 + 8 * ch;
      U16x8 a, bb, c, d, o;
      a.v  = *(const f16x8*)&t0[tb];
      bb.v = *(const f16x8*)&t0[tb + 256];
      c.v  = *(const f16x8*)&t0[tb + 64 * 256];
      d.v  = *(const f16x8*)&t0[tb + 65 * 256];
#pragma unroll
      for (int e2 = 0; e2 < 8; ++e2)
        o.h[e2] = ((a.h[e2] + bb.h[e2]) + (c.h[e2] + d.h[e2])) * (_Float16)0.25f;
      *(f16x8*)&Xs[pp][8 * ch] = o.v;
    }
#pragma unroll
    for (int r = 0; r < 2; ++r) {
      int e = tid + 256 * r;
      int oc = e >> 3, ch = e & 7;
      *(f16x8*)&Ws[oc][8 * ch] = *(const f16x8*)&Wo[(size_t)(o0 + oc) * 256 + k0 + 8 * ch];
    }
    __syncthreads();
#pragma unroll
    for (int ks = 0; ks < 2; ++ks) {
      f16x8 af[2], bf[2];
#pragma unroll
      for (int t = 0; t < 2; ++t) af[t] = *(const f16x8*)&Ws[32 * wr + 16 * t + m][32 * ks + 8 * h];
#pragma unroll
      for (int t = 0; t < 2; ++t) bf[t] = *(const f16x8*)&Xs[32 * wc + 16 * t + m][32 * ks + 8 * h];
#pragma unroll
      for (int ta = 0; ta < 2; ++ta)
#pragma unroll
        for (int tb2 = 0; tb2 < 2; ++tb2)
          acc1[ta][tb2] = __builtin_amdgcn_mfma_f32_16x16x32_f16(af[ta], bf[tb2], acc1[ta][tb2], 0, 0, 0);
    }
  }

  // phase B: pool_x (Cin=128) @ W_res -> acc2
  for (int k0 = 0; k0 < 128; k0 += 64) {
    __syncthreads();
#pragma unroll
    for (int r = 0; r < 2; ++r) {
      int e = tid + 256 * r;
      int pp = e >> 3, ch = e & 7;
      *(f16x8*)&Xs[pp][8 * ch] =
          *(const f16x8*)&pool_x[((size_t)b * 1024 + p0 + pp) * 128 + k0 + 8 * ch];
    }
#pragma unroll
    for (int r = 0; r < 2; ++r) {
      int e = tid + 256 * r;
      int oc = e >> 3, ch = e & 7;
      *(f16x8*)&Ws[oc][8 * ch] = *(const f16x8*)&Wr[(size_t)(o0 + oc) * 128 + k0 + 8 * ch];
    }
    __syncthreads();
#pragma unroll
    for (int ks = 0; ks < 2; ++ks) {
      f16x8 af[2], bf[2];
#pragma unroll
      for (int t = 0; t < 2; ++t) af[t] = *(const f16x8*)&Ws[32 * wr + 16 * t + m][32 * ks + 8 * h];
#pragma unroll
      for (int t = 0; t < 2; ++t) bf[t] = *(const f16x8*)&Xs[32 * wc + 16 * t + m][32 * ks + 8 * h];
#pragma unroll
      for (int ta = 0; ta < 2; ++ta)
#pragma unroll
        for (int tb2 = 0; tb2 < 2; ++tb2)
          acc2[ta][tb2] = __builtin_amdgcn_mfma_f32_16x16x32_f16(af[ta], bf[tb2], acc2[ta][tb2], 0, 0, 0);
    }
  }

  const float al = *alpha;
#pragma unroll
  for (int ta = 0; ta < 2; ++ta)
#pragma unroll
    for (int r = 0; r < 4; ++r) {
      int oc = o0 + 32 * wr + 16 * ta + 4 * h + r;
      float sc = bn[oc] * rsqrtf(bn[768 + oc] + EPS_F);
      float shift = bn[256 + oc] - bn[512 + oc] * sc;
      float ss = sb[b * 512 + oc];
      float bb = sb[b * 512 + 256 + oc];
      float scale = sc * ss;
      shift = shift * ss + bb;
#pragma unroll
      for (int tb2 = 0; tb2 < 2; ++tb2) {
        int p = p0 + 32 * wc + 16 * tb2 + m;
        float v = acc1[ta][tb2][r] * scale + shift + acc2[ta][tb2][r];
        v = v > 0.f ? v : al * v;
        Y32[((size_t)b * 256 + oc) * 1024 + p] = v;
      }
    }
}

// ---------------- axial attention + fused qkv conv, 32 KB LDS (unchanged from R16) ----------------
__global__ void __launch_bounds__(256) axial_attn_kernel(
    const ushort* __restrict__ t0in, const ushort* __restrict__ wqkv,
    const float* __restrict__ bn_qkv,
    const ushort* __restrict__ relimg,
    const float* __restrict__ bn_sim, const float* __restrict__ bn_out,
    ushort* __restrict__ out16) {
  const int tid = threadIdx.x;
  int lin = blockIdx.x;                       // bijective XCD swizzle, bd-major chunks
  int wg = ((lin & 7) << 9) + (lin >> 3);
  const int g  = wg & 15;
  const int bd = wg >> 4;
  const int b  = bd >> 6;
  const int d1 = bd & 63;

  __shared__ __align__(16) char smem[32768];
#define RAA(d, c)  (smem + (d) * 40 + (c) * 2)
#define QKA(i, c)  (smem + 5120 + (i) * 48 + (c) * 2)
#define QEA(i, k)  (smem + 8192 + (i) * 144 + (k) * 2)
#define KEA(j, k)  (smem + 17408 + (j) * 144 + (k) * 2)
#define VCA(c, j)  (smem + 26624 + ((((c) * 128 + (j) * 2)) ^ (((c) & 7) << 4)))
#define RVA(c, d)  (smem + 28672 + ((((c) * 256 + (d) * 2)) ^ (((c) & 7) << 4)))
#define A2A(i, d)  (smem + (i) * 272 + (d) * 2)

  const int lane = tid & 63;
  const int wv   = tid >> 6;
  const int m    = lane & 15;
  const int h    = lane >> 4;
  const int wr   = wv >> 1, wc = wv & 1;

  // ---- P0: copy rel images ----
  {
    const uint4* img = (const uint4*)relimg;
    ((uint4*)smem)[tid] = img[tid];
    if (tid < 64) ((uint4*)smem)[256 + tid] = img[256 + tid];
    ((uint4*)(smem + 28672))[tid] = img[320 + tid];
  }

  // ---- C0: fused qkv conv, double-buffered LDS staging ----
  f32x4 cacc[2];
  cacc[0] = (f32x4){0.f, 0.f, 0.f, 0.f};
  cacc[1] = (f32x4){0.f, 0.f, 0.f, 0.f};
  {
    const ushort* Xb = t0in + ((size_t)b * 4096 + d1) * 256;
    const ushort* Wg = wqkv + ((size_t)(g * 32 + 16 * wr + m)) * 256;
    char* const XS0 = smem + 8192;
    char* const XS1 = smem + 17408;
    const int si = tid >> 3, ssub = tid & 7;
#pragma unroll
    for (int r = 0; r < 2; ++r) {
      int i = si + 32 * r;
      *(f16x8*)(XS0 + i * 144 + ssub * 16) =
          *(const f16x8*)&Xb[(size_t)i * 16384 + 8 * ssub];
    }
    __syncthreads();
#pragma unroll
    for (int c = 0; c < 4; ++c) {
      char* cur = (c & 1) ? XS1 : XS0;
      if (c < 3) {
        char* nxt = (c & 1) ? XS0 : XS1;
#pragma unroll
        for (int r = 0; r < 2; ++r) {
          int i = si + 32 * r;
          *(f16x8*)(nxt + i * 144 + ssub * 16) =
              *(const f16x8*)&Xb[(size_t)i * 16384 + (c + 1) * 64 + 8 * ssub];
        }
      }
#pragma unroll
      for (int ks = 0; ks < 2; ++ks) {
        f16x8 af = *(const f16x8*)&Wg[c * 64 + 32 * ks + 8 * h];
#pragma unroll
        for (int tb = 0; tb < 2; ++tb) {
          int i = 32 * wc + 16 * tb + m;
          f16x8 bf = *(const f16x8*)(cur + i * 144 + (32 * ks + 8 * h) * 2);
          cacc[tb] = __builtin_amdgcn_mfma_f32_16x16x32_f16(af, bf, cacc[tb], 0, 0, 0);
        }
      }
      __syncthreads();
    }
  }
  // C1: epilogue — fold bn_qkv, write QK (wr=0) / VC (wr=1)
  {
    float scl[4], shf[4];
#pragma unroll
    for (int r = 0; r < 4; ++r) {
      int ch = g * 32 + 16 * wr + 4 * h + r;
      float sc = bn_qkv[ch] * rsqrtf(bn_qkv[1536 + ch] + EPS_F);
      scl[r] = sc;
      shf[r] = bn_qkv[512 + ch] - bn_qkv[1024 + ch] * sc;
    }
    if (wr == 0) {
#pragma unroll
      for (int tb = 0; tb < 2; ++tb) {
        int i = 32 * wc + 16 * tb + m;
        U16x4 o;
#pragma unroll
        for (int r = 0; r < 4; ++r) o.u[r] = f2h(cacc[tb][r] * scl[r] + shf[r]);
        *(f16x4*)QKA(i, 4 * h) = o.v;
      }
    } else {
#pragma unroll
      for (int tb = 0; tb < 2; ++tb) {
        int i = 32 * wc + 16 * tb + m;
#pragma unroll
        for (int r = 0; r < 4; ++r)
          *(ushort*)VCA(4 * h + r, i) = f2h(cacc[tb][r] * scl[r] + shf[r]);
      }
    }
  }
  __syncthreads();   // barrier A

  // ---- P1: band-restricted emb GEMM (zeros injected in registers) ----
  {
    const int nt = wv;
    const int n = 16 * nt + m;
    f16x4 bqk = *(const f16x4*)QKA(n, 4 * h);
    const f16x4 z4 = (f16x4){(_Float16)0.f, (_Float16)0.f, (_Float16)0.f, (_Float16)0.f};
    const bool qside = (h < 2);
#pragma unroll
    for (int k = 0; k < 5; ++k) {
      int dt = nt + k;
      f16x4 ar = *(const f16x4*)RAA(16 * dt + m, 4 * h);
      f16x4 arQ = qside ? ar : z4;
      f16x4 arK = qside ? z4 : ar;
      f32x4 dq = __builtin_amdgcn_mfma_f32_16x16x16f16(arQ, bqk, (f32x4){0.f,0.f,0.f,0.f}, 0, 0, 0);
      f32x4 dk = __builtin_amdgcn_mfma_f32_16x16x16f16(arK, bqk, (f32x4){0.f,0.f,0.f,0.f}, 0, 0, 0);
#pragma unroll
      for (int r = 0; r < 4; ++r) {
        int d = 16 * dt + 4 * h + r;
        int i = n - d + 63;
        if (k == 0 || k == 4) {
          if ((unsigned)i < 64u) {
            *(ushort*)QEA(i, n) = f2h(dq[r]);
            *(ushort*)KEA(i, n) = f2h(dk[r]);
          }
        } else {
          *(ushort*)QEA(i, n) = f2h(dq[r]);
          *(ushort*)KEA(i, n) = f2h(dk[r]);
        }
      }
    }
  }
  __syncthreads();   // barrier B

  // ---- P2: sim ----
  f32x4 acc[4];
#pragma unroll
  for (int tj = 0; tj < 4; ++tj) acc[tj] = (f32x4){0.f, 0.f, 0.f, 0.f};
  {
    const int ia = 16 * wv + m;
    f16x8 af0 = *(const f16x8*)QEA(ia, 8 * h);
    f16x8 af1 = *(const f16x8*)QEA(ia, 32 + 8 * h);
#pragma unroll
    for (int tj = 0; tj < 4; ++tj) {
      int j = 16 * tj + m;
      f16x8 bf0 = *(const f16x8*)KEA(j, 8 * h);
      f16x8 bf1 = *(const f16x8*)KEA(j, 32 + 8 * h);
      acc[tj] = __builtin_amdgcn_mfma_f32_16x16x32_f16(af0, bf0, acc[tj], 0, 0, 0);
      acc[tj] = __builtin_amdgcn_mfma_f32_16x16x32_f16(af1, bf1, acc[tj], 0, 0, 0);
    }
  }

  float s_qk = bn_sim[g]      * rsqrtf(bn_sim[144 + g] + EPS_F);
  float s_qe = bn_sim[16 + g] * rsqrtf(bn_sim[160 + g] + EPS_F);
  float s_ke = bn_sim[32 + g] * rsqrtf(bn_sim[176 + g] + EPS_F);
  float sh   = (bn_sim[48 + g] - bn_sim[96 + g]  * s_qk)
             + (bn_sim[64 + g] - bn_sim[112 + g] * s_qe)
             + (bn_sim[80 + g] - bn_sim[128 + g] * s_ke);

  const int ib = 16 * wv + 4 * h;
  float sv[4][4];
#pragma unroll
  for (int tj = 0; tj < 4; ++tj) {
    int j = 16 * tj + m;
    f16x4 qe4 = *(const f16x4*)QEA(j, ib);
    f16x4 ke4 = *(const f16x4*)KEA(j, ib);
#pragma unroll
    for (int r = 0; r < 4; ++r)
      sv[tj][r] = acc[tj][r] * s_qk + (float)qe4[r] * s_qe + (float)ke4[r] * s_ke + sh;
  }

  // ---- P3: softmax over j ----
  float p[4][4];
  {
    float mx[4];
#pragma unroll
    for (int r = 0; r < 4; ++r) {
      float v = fmaxf(fmaxf(sv[0][r], sv[1][r]), fmaxf(sv[2][r], sv[3][r]));
      v = fmaxf(v, __shfl_xor(v, 1));
      v = fmaxf(v, __shfl_xor(v, 2));
      v = fmaxf(v, __shfl_xor(v, 4));
      v = fmaxf(v, __shfl_xor(v, 8));
      mx[r] = v;
    }
#pragma unroll
    for (int r = 0; r < 4; ++r) {
      float ssum = 0.f;
#pragma unroll
      for (int tj = 0; tj < 4; ++tj) {
        p[tj][r] = __expf(sv[tj][r] - mx[r]);
        ssum += p[tj][r];
      }
      ssum += __shfl_xor(ssum, 1);
      ssum += __shfl_xor(ssum, 2);
      ssum += __shfl_xor(ssum, 4);
      ssum += __shfl_xor(ssum, 8);
      float inv = 1.f / ssum;
#pragma unroll
      for (int tj = 0; tj < 4; ++tj) p[tj][r] *= inv;
    }
  }

  __syncthreads();   // barrier C

  // ---- P4: wave-private zero of A2 rows [16wv,16wv+16), then scatter ----
  {
    uint4 z = make_uint4(0u, 0u, 0u, 0u);
    uint4* base = (uint4*)(smem + wv * 4352);
#pragma unroll
    for (int u = 0; u < 4; ++u) base[lane + 64 * u] = z;
    if (lane < 16) base[lane + 256] = z;
  }
#pragma unroll
  for (int tj = 0; tj < 4; ++tj) {
    int j = 16 * tj + m;
#pragma unroll
    for (int r = 0; r < 4; ++r) {
      int i = ib + r;
      *(ushort*)A2A(i, i - j + 63) = f2h(p[tj][r]);
    }
  }

  // ---- P5: att / att_e ----
  f32x4 accA = (f32x4){0.f, 0.f, 0.f, 0.f};
  f32x4 accE = (f32x4){0.f, 0.f, 0.f, 0.f};
  {
    const int ia = 16 * wv + m;
#pragma unroll
    for (int ks = 0; ks < 2; ++ks) {
      U16x8 pa;
#pragma unroll
      for (int e = 0; e < 8; ++e) {
        int j = 32 * ks + 8 * h + e;
        pa.u[e] = *(ushort*)A2A(ia, ia - j + 63);
      }
      f16x8 vb = *(const f16x8*)VCA(m, 32 * ks + 8 * h);
      accA = __builtin_amdgcn_mfma_f32_16x16x32_f16(pa.v, vb, accA, 0, 0, 0);
    }
#pragma unroll
    for (int ks = 0; ks < 4; ++ks) {
      f16x8 pe = *(const f16x8*)A2A(ia, 32 * ks + 8 * h);
      f16x8 rv = *(const f16x8*)RVA(m, 32 * ks + 8 * h);
      accE = __builtin_amdgcn_mfma_f32_16x16x32_f16(pe, rv, accE, 0, 0, 0);
    }
  }

  // ---- P6: fold bn_out, pixel-major write ----
  {
    int oc = g * 16 + m;
    int c0 = 2 * oc, c1 = c0 + 1;
    float sc0 = bn_out[c0] * rsqrtf(bn_out[1536 + c0] + EPS_F);
    float sh0 = bn_out[512 + c0] - bn_out[1024 + c0] * sc0;
    float sc1 = bn_out[c1] * rsqrtf(bn_out[1536 + c1] + EPS_F);
    float sh1 = bn_out[512 + c1] - bn_out[1024 + c1] * sc1;
    float vv[4];
    vv[0] = accA[0] * sc0 + accE[0] * sc1 + sh0 + sh1;
    vv[1] = accA[1] * sc0 + accE[1] * sc1 + sh0 + sh1;
    vv[2] = accA[2] * sc0 + accE[2] * sc1 + sh0 + sh1;
    vv[3] = accA[3] * sc0 + accE[3] * sc1 + sh0 + sh1;
    size_t base = ((size_t)b * 4096 + (size_t)d1 * 64 + ib) * 256 + oc;
#pragma unroll
    for (int r = 0; r < 4; ++r)
      out16[base + (size_t)r * 256] = f2h(vv[r]);
  }
#undef RAA
#undef QKA
#undef QEA
#undef KEA
#undef VCA
#undef RVA
#undef A2A
}

extern "C" void kernel_launch(void* const* d_in, const int* in_sizes, int n_in,
                              void* d_out, int out_size, void* d_ws, size_t ws_size,
                              hipStream_t stream) {
  const float* x         = (const float*)d_in[0];
  const float* latent    = (const float*)d_in[1];
  const float* w_in      = (const float*)d_in[2];
  const float* bn_in     = (const float*)d_in[3];
  const float* lin_in    = (const float*)d_in[4];
  const float* alpha_in  = (const float*)d_in[5];
  const float* a0_wqkv   = (const float*)d_in[6];
  const float* a0_bn_qkv = (const float*)d_in[7];
  const float* a0_bn_sim = (const float*)d_in[8];
  const float* a0_bn_out = (const float*)d_in[9];
  const float* a0_rel    = (const float*)d_in[10];
  const float* a1_wqkv   = (const float*)d_in[11];
  const float* a1_bn_qkv = (const float*)d_in[12];
  const float* a1_bn_sim = (const float*)d_in[13];
  const float* a1_bn_out = (const float*)d_in[14];
  const float* a1_rel    = (const float*)d_in[15];
  const float* w_out     = (const float*)d_in[16];
  const float* bn_outp   = (const float*)d_in[17];
  const float* lin_out   = (const float*)d_in[18];
  const float* w_res     = (const float*)d_in[19];
  const float* alpha_fin = (const float*)d_in[20];

  float* ws = (float*)d_ws;
  float* sb_in  = ws;                          // 2048 f
  float* sb_out = ws + 2048;                   // 2048 f
  ushort* w16   = (ushort*)(ws + 4096);        // 393216 u16
  ushort* relimg = w16 + 393216;               // 9216 u16 (2 x 4608)
  ushort* x16   = relimg + 9216;               // 2097152 u16 (b,4096,128)
  ushort* t0    = x16 + 2097152;               // 4194304 u16 (b,4096,256)
  ushort* t1    = t0 + 4194304;                // 4194304 u16 ping-pong
  ushort* pool_x = t1 + 4194304;               // 524288 u16  (b,1024,128)

  ushort* w_in16  = w16;
  ushort* a0w16   = w16 + 32768;
  ushort* a1w16   = w16 + 163840;
  ushort* w_out16 = w16 + 294912;
  ushort* w_res16 = w16 + 360448;
  ushort* rimg_a  = relimg;
  ushort* rimg_b  = relimg + 4608;

  // prep: weights/sb/relimg + cvtT(x) + poolx(x)
  prep_kernel<<<2612, 256, 0, stream>>>(w_in, a0_wqkv, a1_wqkv, w_out, w_res,
                                        latent, lin_in, lin_out, a0_rel, a1_rel,
                                        x, w16, relimg, sb_in, sb_out, x16, pool_x);

  // conv_in + cbn + prelu -> t0 (pixel-major, p = h*64+w), BN=64 tiles
  conv_mfma_kernel<11><<<dim3(64, 4, 4), 256, 0, stream>>>(
      x16, w_in16, t0, 128, 256, 4096, bn_in, sb_in, alpha_in);

  // axial 0 over H (i=h, d1=w), fused qkv conv: t0 -> t1 (out p = w*64+h)
  axial_attn_kernel<<<4096, 256, 0, stream>>>(
      t0, a0w16, a0_bn_qkv, rimg_a, a0_bn_sim, a0_bn_out, t1);

  // axial 1 over W (i=w, d1=h), fused qkv conv: t1 -> t0 (out p = h*64+w, std)
  axial_attn_kernel<<<4096, 256, 0, stream>>>(
      t1, a1w16, a1_bn_qkv, rimg_b, a1_bn_sim, a1_bn_out, t0);

  // fused: pool(t0)@W_out (cbn) + pool_x@W_res, prelu -> d_out (f32 chan-major)
  final_fused_kernel<<<dim3(16, 4, 4), 256, 0, stream>>>(
      t0, pool_x, w_out16, w_res16, (float*)d_out, bn_outp, sb_out, alpha_fin);
}